// Round 3
// baseline (5003.638 us; speedup 1.0000x reference)
//
#include <hip/hip_runtime.h>
#include <cstdint>
#include <cstddef>

// ---------------------------------------------------------------------------
// EncodeProcessDecode GNN, fp32.
// Structure: c-chunked register-tile MLPs. GEMM1 (K -> 128 hidden) computes h
// in chunks of 32 with dynamic k-loops (weights = wave-uniform float4 loads,
// 4 FMA/load). GEMM2 (128 -> 64) bounces each relu'd h-chunk through a
// per-thread LDS column (sb[k][tid], conflict-free, no barriers needed for
// correctness) so k can be a dynamic loop: 64 FMA per uniform W1-row load.
// Aggregation accumulates in fp64 -> bit-stable under elist order permutation
// (atomic CSR fill is order-nondeterministic across graph replays).
// ---------------------------------------------------------------------------

__global__ void k_zero(int* __restrict__ p, int n) {
    int i = blockIdx.x * 256 + threadIdx.x;
    if (i < n) p[i] = 0;
}

// ---------------- CSR build ----------------

__global__ void k_hist(const int* __restrict__ dst, int* __restrict__ counts, int E) {
    int e = blockIdx.x * 256 + threadIdx.x;
    if (e < E) atomicAdd(&counts[dst[e]], 1);
}

__global__ __launch_bounds__(1024) void k_scan(
    const int* __restrict__ counts, int* __restrict__ row_off,
    int* __restrict__ cursor, float* __restrict__ inv_cnt, int N) {
    __shared__ int wsum[16];
    int t = threadIdx.x;
    int wave = t >> 6, lane = t & 63;
    int carry = 0;
    for (int base = 0; base < N; base += 1024) {
        int i = base + t;
        int v = (i < N) ? counts[i] : 0;
        int s = v;
        #pragma unroll
        for (int off = 1; off < 64; off <<= 1) {
            int u = __shfl_up(s, off, 64);
            if (lane >= off) s += u;
        }
        if (lane == 63) wsum[wave] = s;
        __syncthreads();
        int wpre = 0, full = 0;
        #pragma unroll
        for (int wv = 0; wv < 16; wv++) {
            int x = wsum[wv];
            full += x;
            if (wv < wave) wpre += x;
        }
        if (i < N) {
            int excl = carry + wpre + s - v;
            row_off[i] = excl;
            cursor[i]  = excl;
            inv_cnt[i] = 1.0f / (float)((v > 0) ? v : 1);
        }
        carry += full;
        __syncthreads();
    }
    if (t == 0) row_off[N] = carry;
}

__global__ void k_fill(const int* __restrict__ dst, int* __restrict__ cursor,
                       int* __restrict__ edge_list, int E) {
    int e = blockIdx.x * 256 + threadIdx.x;
    if (e < E) {
        int pos = atomicAdd(&cursor[dst[e]], 1);
        edge_list[pos] = e;
    }
}

// ---------------- encoder helper table ----------------

// embW[p][c] = enc_n_b0[c] + sum_k emb[p][k] * W0[(31+k)][c]   (p in {0,1})
__global__ void k_embW(const float* __restrict__ emb, const float* __restrict__ W0,
                       const float* __restrict__ b0, float* __restrict__ embW) {
    int c = threadIdx.x;  // 128 threads
    #pragma unroll
    for (int p = 0; p < 2; p++) {
        float acc = b0[c];
        #pragma unroll
        for (int k = 0; k < 16; k++)
            acc = fmaf(emb[p * 16 + k], W0[(31 + k) * 128 + c], acc);
        embW[p * 128 + c] = acc;
    }
}

// ---------------- GEMM building blocks ----------------

// h[0..31] += a[0..4*kk4) @ W[0..4*kk4)][cbase..cbase+32)   (W rows are 128 wide)
__device__ __forceinline__ void g1_accum32(
    const float4* __restrict__ a4, int kk4,
    const float* __restrict__ W, int cbase, float* __restrict__ h) {
    #pragma clang loop unroll(disable)
    for (int kk = 0; kk < kk4; kk++) {
        float4 a = a4[kk];
        const float* wr = W + (size_t)kk * 4 * 128 + cbase;
        const float4* w0 = reinterpret_cast<const float4*>(wr);
        const float4* w1 = reinterpret_cast<const float4*>(wr + 128);
        const float4* w2 = reinterpret_cast<const float4*>(wr + 256);
        const float4* w3 = reinterpret_cast<const float4*>(wr + 384);
        #pragma unroll
        for (int cg = 0; cg < 8; cg++) {
            float4 p = w0[cg], q = w1[cg], r = w2[cg], s = w3[cg];
            h[cg*4+0] = fmaf(a.w, s.x, fmaf(a.z, r.x, fmaf(a.y, q.x, fmaf(a.x, p.x, h[cg*4+0]))));
            h[cg*4+1] = fmaf(a.w, s.y, fmaf(a.z, r.y, fmaf(a.y, q.y, fmaf(a.x, p.y, h[cg*4+1]))));
            h[cg*4+2] = fmaf(a.w, s.z, fmaf(a.z, r.z, fmaf(a.y, q.z, fmaf(a.x, p.z, h[cg*4+2]))));
            h[cg*4+3] = fmaf(a.w, s.w, fmaf(a.z, r.w, fmaf(a.y, q.w, fmaf(a.x, p.w, h[cg*4+3]))));
        }
    }
}

// h[0..31] += x*W[0][c..] + y*W[1][c..] + z*W[2][c..]
__device__ __forceinline__ void g1_tail3(
    float x, float y, float z, const float* __restrict__ W, int cbase,
    float* __restrict__ h) {
    const float4* w0 = reinterpret_cast<const float4*>(W + cbase);
    const float4* w1 = reinterpret_cast<const float4*>(W + 128 + cbase);
    const float4* w2 = reinterpret_cast<const float4*>(W + 256 + cbase);
    #pragma unroll
    for (int cg = 0; cg < 8; cg++) {
        float4 p = w0[cg], q = w1[cg], r = w2[cg];
        h[cg*4+0] = fmaf(z, r.x, fmaf(y, q.x, fmaf(x, p.x, h[cg*4+0])));
        h[cg*4+1] = fmaf(z, r.y, fmaf(y, q.y, fmaf(x, p.y, h[cg*4+1])));
        h[cg*4+2] = fmaf(z, r.z, fmaf(y, q.z, fmaf(x, p.z, h[cg*4+2])));
        h[cg*4+3] = fmaf(z, r.w, fmaf(y, q.w, fmaf(x, p.w, h[cg*4+3])));
    }
}

// o[0..64) += hc[0..32) @ W1[kbase..kbase+32)][0..64)  (row stride rs floats)
// hc is bounced through per-thread LDS column so k can be dynamic.
__device__ __forceinline__ void g2_accum64(
    float* __restrict__ sb, const float* __restrict__ hc,
    const float* __restrict__ W1, int kbase, int rs, float* __restrict__ o) {
    int t = threadIdx.x;
    #pragma unroll
    for (int k = 0; k < 32; k++) sb[k * 256 + t] = hc[k];
    __syncthreads();
    #pragma clang loop unroll(disable)
    for (int k = 0; k < 32; k++) {
        float hk = sb[k * 256 + t];
        const float4* w = reinterpret_cast<const float4*>(W1 + (size_t)(kbase + k) * rs);
        #pragma unroll
        for (int cg = 0; cg < 16; cg++) {
            float4 wv = w[cg];
            o[cg*4+0] = fmaf(hk, wv.x, o[cg*4+0]);
            o[cg*4+1] = fmaf(hk, wv.y, o[cg*4+1]);
            o[cg*4+2] = fmaf(hk, wv.z, o[cg*4+2]);
            o[cg*4+3] = fmaf(hk, wv.w, o[cg*4+3]);
        }
    }
    __syncthreads();
}

// ---------------- node encoder (tail only) ----------------

__global__ __launch_bounds__(256, 3) void k_enc_node_tail(
    const float* __restrict__ nodeF, const float* __restrict__ embW,
    const float* __restrict__ W0, const float* __restrict__ W1,
    const float* __restrict__ b1, float* __restrict__ nodeT, int N) {
    __shared__ float sb[32 * 256];
    int n = blockIdx.x * 256 + threadIdx.x;
    bool valid = n < N;
    int nc = valid ? n : N - 1;
    const float4* nf4 = reinterpret_cast<const float4*>(nodeF + (size_t)nc * 32);
    float4 v7 = nf4[7];
    int p = (int)(v7.w + 0.5f);
    const float4* ew = reinterpret_cast<const float4*>(embW + p * 128);

    float o[64];
    const float4* bv = reinterpret_cast<const float4*>(b1 + 64);
    #pragma unroll
    for (int i = 0; i < 16; i++) {
        float4 b = bv[i];
        o[4*i+0] = b.x; o[4*i+1] = b.y; o[4*i+2] = b.z; o[4*i+3] = b.w;
    }
    #pragma unroll
    for (int ch = 0; ch < 4; ch++) {
        int cbase = ch * 32;
        float h[32];
        #pragma unroll
        for (int i = 0; i < 8; i++) {
            float4 u = ew[ch*8 + i];
            h[4*i+0] = u.x; h[4*i+1] = u.y; h[4*i+2] = u.z; h[4*i+3] = u.w;
        }
        g1_accum32(nf4, 7, W0, cbase, h);               // feats 0..27
        g1_tail3(v7.x, v7.y, v7.z, W0 + 28*128, cbase, h); // feats 28..30
        #pragma unroll
        for (int i = 0; i < 32; i++) h[i] = fmaxf(h[i], 0.0f);
        g2_accum64(sb, h, W1 + 64, cbase, 128, o);      // W1 cols 64..127
    }
    if (valid) {
        float4* out4 = reinterpret_cast<float4*>(nodeT + (size_t)n * 64);
        #pragma unroll
        for (int i = 0; i < 16; i++)
            out4[i] = make_float4(o[4*i], o[4*i+1], o[4*i+2], o[4*i+3]);
    }
}

// ---------------- edge encoder ----------------

__global__ __launch_bounds__(256, 3) void k_enc_edge(
    const float* __restrict__ edgeF,
    const float* __restrict__ W0, const float* __restrict__ b0,
    const float* __restrict__ W1, const float* __restrict__ b1,
    float* __restrict__ edgeT, int E) {
    __shared__ float sb[32 * 256];
    int e = blockIdx.x * 256 + threadIdx.x;
    bool valid = e < E;
    int ec = valid ? e : E - 1;
    float x0 = edgeF[(size_t)ec * 3 + 0];
    float x1 = edgeF[(size_t)ec * 3 + 1];
    float x2 = edgeF[(size_t)ec * 3 + 2];

    float o[64];
    const float4* bv = reinterpret_cast<const float4*>(b1 + 64);
    #pragma unroll
    for (int i = 0; i < 16; i++) {
        float4 b = bv[i];
        o[4*i+0] = b.x; o[4*i+1] = b.y; o[4*i+2] = b.z; o[4*i+3] = b.w;
    }
    #pragma unroll
    for (int ch = 0; ch < 4; ch++) {
        int cbase = ch * 32;
        float h[32];
        const float4* b0v = reinterpret_cast<const float4*>(b0 + cbase);
        #pragma unroll
        for (int i = 0; i < 8; i++) {
            float4 b = b0v[i];
            h[4*i+0] = b.x; h[4*i+1] = b.y; h[4*i+2] = b.z; h[4*i+3] = b.w;
        }
        g1_tail3(x0, x1, x2, W0, cbase, h);
        #pragma unroll
        for (int i = 0; i < 32; i++) h[i] = fmaxf(h[i], 0.0f);
        g2_accum64(sb, h, W1 + 64, cbase, 128, o);
    }
    if (valid) {
        float4* out4 = reinterpret_cast<float4*>(edgeT + (size_t)e * 64);
        #pragma unroll
        for (int i = 0; i < 16; i++)
            out4[i] = make_float4(o[4*i], o[4*i+1], o[4*i+2], o[4*i+3]);
    }
}

// ------------- per-step node projections (plan A) ---------------------------

__global__ __launch_bounds__(256, 4) void k_node_pre(
    const float* __restrict__ nodeT, const float* __restrict__ W0,
    const float* __restrict__ b0,
    float* __restrict__ Pd, float* __restrict__ Ps, int N) {
    int n = blockIdx.x * 256 + threadIdx.x;
    bool valid = n < N;
    int nc = valid ? n : N - 1;
    const float4* a4 = reinterpret_cast<const float4*>(nodeT + (size_t)nc * 64);

    #pragma unroll
    for (int ch = 0; ch < 4; ch++) {
        int cbase = ch * 32;
        float h[32];
        const float4* b0v = reinterpret_cast<const float4*>(b0 + cbase);
        #pragma unroll
        for (int i = 0; i < 8; i++) {
            float4 b = b0v[i];
            h[4*i+0] = b.x; h[4*i+1] = b.y; h[4*i+2] = b.z; h[4*i+3] = b.w;
        }
        g1_accum32(a4, 16, W0 + 64*128, cbase, h);
        if (valid) {
            float4* o4 = reinterpret_cast<float4*>(Pd + (size_t)n * 128 + cbase);
            #pragma unroll
            for (int i = 0; i < 8; i++)
                o4[i] = make_float4(h[4*i], h[4*i+1], h[4*i+2], h[4*i+3]);
        }
    }
    #pragma unroll
    for (int ch = 0; ch < 4; ch++) {
        int cbase = ch * 32;
        float h[32];
        #pragma unroll
        for (int i = 0; i < 32; i++) h[i] = 0.0f;
        g1_accum32(a4, 16, W0 + 128*128, cbase, h);
        if (valid) {
            float4* o4 = reinterpret_cast<float4*>(Ps + (size_t)n * 128 + cbase);
            #pragma unroll
            for (int i = 0; i < 8; i++)
                o4[i] = make_float4(h[4*i], h[4*i+1], h[4*i+2], h[4*i+3]);
        }
    }
}

// ------------- plan A edge core ---------------------------------------------

__global__ __launch_bounds__(256, 3) void k_edge_core_A(
    float* __restrict__ edgeT,
    const float* __restrict__ Pd, const float* __restrict__ Ps,
    const int* __restrict__ src, const int* __restrict__ dst,
    const float* __restrict__ W0, const float* __restrict__ W1,
    const float* __restrict__ b1, int E) {
    __shared__ float sb[32 * 256];
    int e = blockIdx.x * 256 + threadIdx.x;
    bool valid = e < E;
    int ec = valid ? e : E - 1;
    int d = dst[ec], s = src[ec];
    const float4* a4  = reinterpret_cast<const float4*>(edgeT + (size_t)ec * 64);
    const float4* pd4 = reinterpret_cast<const float4*>(Pd + (size_t)d * 128);
    const float4* ps4 = reinterpret_cast<const float4*>(Ps + (size_t)s * 128);

    float o[64];
    const float4* bv = reinterpret_cast<const float4*>(b1);
    #pragma unroll
    for (int i = 0; i < 16; i++) {
        float4 b = bv[i];
        o[4*i+0] = b.x; o[4*i+1] = b.y; o[4*i+2] = b.z; o[4*i+3] = b.w;
    }
    #pragma unroll
    for (int ch = 0; ch < 4; ch++) {
        int cbase = ch * 32;
        float h[32];
        #pragma unroll
        for (int i = 0; i < 8; i++) {
            float4 u = pd4[ch*8 + i];
            float4 v = ps4[ch*8 + i];
            h[4*i+0] = u.x + v.x; h[4*i+1] = u.y + v.y;
            h[4*i+2] = u.z + v.z; h[4*i+3] = u.w + v.w;
        }
        g1_accum32(a4, 16, W0, cbase, h);
        #pragma unroll
        for (int i = 0; i < 32; i++) h[i] = fmaxf(h[i], 0.0f);
        g2_accum64(sb, h, W1, cbase, 64, o);
    }
    if (valid) {
        float4* eo4 = reinterpret_cast<float4*>(edgeT + (size_t)e * 64);
        #pragma unroll
        for (int i = 0; i < 16; i++) {
            float4 t = a4[i];
            t.x += o[4*i+0]; t.y += o[4*i+1];
            t.z += o[4*i+2]; t.w += o[4*i+3];
            eo4[i] = t;
        }
    }
}

// ------------- plan B edge core (no Pd/Ps; inline gather) -------------------

__global__ __launch_bounds__(256, 3) void k_edge_core_B(
    float* __restrict__ edgeT, const float* __restrict__ nodeT,
    const int* __restrict__ src, const int* __restrict__ dst,
    const float* __restrict__ W0, const float* __restrict__ b0,
    const float* __restrict__ W1, const float* __restrict__ b1, int E) {
    __shared__ float sb[32 * 256];
    int e = blockIdx.x * 256 + threadIdx.x;
    bool valid = e < E;
    int ec = valid ? e : E - 1;
    int d = dst[ec], s = src[ec];
    const float4* a4 = reinterpret_cast<const float4*>(edgeT + (size_t)ec * 64);
    const float4* d4 = reinterpret_cast<const float4*>(nodeT + (size_t)d * 64);
    const float4* s4 = reinterpret_cast<const float4*>(nodeT + (size_t)s * 64);

    float o[64];
    const float4* bv = reinterpret_cast<const float4*>(b1);
    #pragma unroll
    for (int i = 0; i < 16; i++) {
        float4 b = bv[i];
        o[4*i+0] = b.x; o[4*i+1] = b.y; o[4*i+2] = b.z; o[4*i+3] = b.w;
    }
    #pragma unroll
    for (int ch = 0; ch < 4; ch++) {
        int cbase = ch * 32;
        float h[32];
        const float4* b0v = reinterpret_cast<const float4*>(b0 + cbase);
        #pragma unroll
        for (int i = 0; i < 8; i++) {
            float4 b = b0v[i];
            h[4*i+0] = b.x; h[4*i+1] = b.y; h[4*i+2] = b.z; h[4*i+3] = b.w;
        }
        g1_accum32(a4, 16, W0, cbase, h);
        g1_accum32(d4, 16, W0 + 64*128, cbase, h);
        g1_accum32(s4, 16, W0 + 128*128, cbase, h);
        #pragma unroll
        for (int i = 0; i < 32; i++) h[i] = fmaxf(h[i], 0.0f);
        g2_accum64(sb, h, W1, cbase, 64, o);
    }
    if (valid) {
        float4* eo4 = reinterpret_cast<float4*>(edgeT + (size_t)e * 64);
        #pragma unroll
        for (int i = 0; i < 16; i++) {
            float4 t = a4[i];
            t.x += o[4*i+0]; t.y += o[4*i+1];
            t.z += o[4*i+2]; t.w += o[4*i+3];
            eo4[i] = t;
        }
    }
}

// ------------- mean aggregation (fp64 accumulate -> order-invariant) --------

__global__ __launch_bounds__(256) void k_agg(
    const float* __restrict__ edgeT, const int* __restrict__ row_off,
    const int* __restrict__ edge_list, const float* __restrict__ inv_cnt,
    float* __restrict__ aggT, int N) {
    int n = blockIdx.x * 4 + (threadIdx.x >> 6);
    int lane = threadIdx.x & 63;
    if (n >= N) return;
    int beg = row_off[n], end = row_off[n + 1];
    double s = 0.0;
    for (int idx = beg; idx < end; idx++) {
        int e = edge_list[idx];
        s += (double)edgeT[(size_t)e * 64 + lane];
    }
    aggT[(size_t)n * 64 + lane] = (float)(s * (double)inv_cnt[n]);
}

// ------------- node core ----------------------------------------------------

__global__ __launch_bounds__(256, 3) void k_node_core(
    const float* __restrict__ aggT, float* __restrict__ nodeT,
    const float* __restrict__ W0, const float* __restrict__ b0,
    const float* __restrict__ W1, const float* __restrict__ b1, int N) {
    __shared__ float sb[32 * 256];
    int n = blockIdx.x * 256 + threadIdx.x;
    bool valid = n < N;
    int nc = valid ? n : N - 1;
    const float4* g4 = reinterpret_cast<const float4*>(aggT + (size_t)nc * 64);
    const float4* t4 = reinterpret_cast<const float4*>(nodeT + (size_t)nc * 64);

    float o[64];
    const float4* bv = reinterpret_cast<const float4*>(b1);
    #pragma unroll
    for (int i = 0; i < 16; i++) {
        float4 b = bv[i];
        o[4*i+0] = b.x; o[4*i+1] = b.y; o[4*i+2] = b.z; o[4*i+3] = b.w;
    }
    #pragma unroll
    for (int ch = 0; ch < 4; ch++) {
        int cbase = ch * 32;
        float h[32];
        const float4* b0v = reinterpret_cast<const float4*>(b0 + cbase);
        #pragma unroll
        for (int i = 0; i < 8; i++) {
            float4 b = b0v[i];
            h[4*i+0] = b.x; h[4*i+1] = b.y; h[4*i+2] = b.z; h[4*i+3] = b.w;
        }
        g1_accum32(g4, 16, W0, cbase, h);
        g1_accum32(t4, 16, W0 + 64*128, cbase, h);
        #pragma unroll
        for (int i = 0; i < 32; i++) h[i] = fmaxf(h[i], 0.0f);
        g2_accum64(sb, h, W1, cbase, 64, o);
    }
    if (valid) {
        float4* nt4 = reinterpret_cast<float4*>(nodeT + (size_t)n * 64);
        #pragma unroll
        for (int i = 0; i < 16; i++) {
            float4 t = t4[i];
            t.x += o[4*i+0]; t.y += o[4*i+1];
            t.z += o[4*i+2]; t.w += o[4*i+3];
            nt4[i] = t;
        }
    }
}

// ------------- decoder (recomputes encoder head) ----------------------------

__global__ __launch_bounds__(256, 2) void k_decode(
    const float* __restrict__ nodeF, const float* __restrict__ embW,
    const float* __restrict__ encW0, const float* __restrict__ encW1,
    const float* __restrict__ encb1, const float* __restrict__ nodeT,
    const float* __restrict__ W0, const float* __restrict__ b0,
    const float* __restrict__ W1, const float* __restrict__ b1,
    float* __restrict__ out, int N) {
    __shared__ float sb[64 * 256];
    int t = threadIdx.x;
    int n = blockIdx.x * 256 + t;
    bool valid = n < N;
    int nc = valid ? n : N - 1;
    const float4* nf4 = reinterpret_cast<const float4*>(nodeF + (size_t)nc * 32);
    const float4* t4  = reinterpret_cast<const float4*>(nodeT + (size_t)nc * 64);
    float4 v7 = nf4[7];
    int p = (int)(v7.w + 0.5f);
    const float4* ew = reinterpret_cast<const float4*>(embW + p * 128);

    // encoder head = encb1[0:64] + relu(enc hidden) @ encW1[:, 0:64]
    float head[64];
    const float4* ebv = reinterpret_cast<const float4*>(encb1);
    #pragma unroll
    for (int i = 0; i < 16; i++) {
        float4 b = ebv[i];
        head[4*i+0] = b.x; head[4*i+1] = b.y; head[4*i+2] = b.z; head[4*i+3] = b.w;
    }
    #pragma unroll
    for (int ch = 0; ch < 4; ch++) {
        int cbase = ch * 32;
        float h[32];
        #pragma unroll
        for (int i = 0; i < 8; i++) {
            float4 u = ew[ch*8 + i];
            h[4*i+0] = u.x; h[4*i+1] = u.y; h[4*i+2] = u.z; h[4*i+3] = u.w;
        }
        g1_accum32(nf4, 7, encW0, cbase, h);
        g1_tail3(v7.x, v7.y, v7.z, encW0 + 28*128, cbase, h);
        #pragma unroll
        for (int i = 0; i < 32; i++) h[i] = fmaxf(h[i], 0.0f);
        g2_accum64(sb, h, encW1, cbase, 128, head);
    }

    // stash head in per-thread LDS column (rows 0..63)
    #pragma unroll
    for (int k = 0; k < 64; k++) sb[k * 256 + t] = head[k];
    __syncthreads();

    // decoder hidden: h2 = b0 + head@W0[0:64] + nodeT@W0[64:128]
    float h2[128];
    #pragma unroll
    for (int ch = 0; ch < 4; ch++) {
        int cbase = ch * 32;
        float* hc = &h2[ch * 32];
        const float4* b0v = reinterpret_cast<const float4*>(b0 + cbase);
        #pragma unroll
        for (int i = 0; i < 8; i++) {
            float4 b = b0v[i];
            hc[4*i+0] = b.x; hc[4*i+1] = b.y; hc[4*i+2] = b.z; hc[4*i+3] = b.w;
        }
        #pragma clang loop unroll(disable)
        for (int k = 0; k < 64; k++) {
            float hk = sb[k * 256 + t];
            const float4* w = reinterpret_cast<const float4*>(W0 + (size_t)k * 128 + cbase);
            #pragma unroll
            for (int cg = 0; cg < 8; cg++) {
                float4 wv = w[cg];
                hc[cg*4+0] = fmaf(hk, wv.x, hc[cg*4+0]);
                hc[cg*4+1] = fmaf(hk, wv.y, hc[cg*4+1]);
                hc[cg*4+2] = fmaf(hk, wv.z, hc[cg*4+2]);
                hc[cg*4+3] = fmaf(hk, wv.w, hc[cg*4+3]);
            }
        }
        g1_accum32(t4, 16, W0 + 64*128, cbase, hc);
    }
    __syncthreads();   // head columns no longer needed

    // out3 = b1 + relu(h2) @ W1  (bounce relu'd chunks, rows 0..31)
    float o0 = b1[0], o1 = b1[1], o2 = b1[2];
    #pragma unroll
    for (int ch = 0; ch < 4; ch++) {
        int kb = ch * 32;
        #pragma unroll
        for (int k = 0; k < 32; k++) sb[k * 256 + t] = fmaxf(h2[kb + k], 0.0f);
        __syncthreads();
        #pragma clang loop unroll(disable)
        for (int k = 0; k < 32; k++) {
            float hk = sb[k * 256 + t];
            const float* w = W1 + (size_t)(kb + k) * 3;
            o0 = fmaf(hk, w[0], o0);
            o1 = fmaf(hk, w[1], o1);
            o2 = fmaf(hk, w[2], o2);
        }
        __syncthreads();
    }
    if (valid) {
        out[(size_t)n * 3 + 0] = o0;
        out[(size_t)n * 3 + 1] = o1;
        out[(size_t)n * 3 + 2] = o2;
    }
}

// ---------------------------------------------------------------------------

extern "C" void kernel_launch(void* const* d_in, const int* in_sizes, int n_in,
                              void* d_out, int out_size, void* d_ws, size_t ws_size,
                              hipStream_t stream) {
    const int*   edge_index = (const int*)  d_in[0];
    const float* nodeF      = (const float*)d_in[1];
    const float* edgeF      = (const float*)d_in[2];
    const float* emb        = (const float*)d_in[3];
    const float* enc_n_W0   = (const float*)d_in[4];
    const float* enc_n_b0   = (const float*)d_in[5];
    const float* enc_n_W1   = (const float*)d_in[6];
    const float* enc_n_b1   = (const float*)d_in[7];
    const float* enc_e_W0   = (const float*)d_in[8];
    const float* enc_e_b0   = (const float*)d_in[9];
    const float* enc_e_W1   = (const float*)d_in[10];
    const float* enc_e_b1   = (const float*)d_in[11];
    const float* core_e_W0  = (const float*)d_in[12];
    const float* core_e_b0  = (const float*)d_in[13];
    const float* core_e_W1  = (const float*)d_in[14];
    const float* core_e_b1  = (const float*)d_in[15];
    const float* core_n_W0  = (const float*)d_in[16];
    const float* core_n_b0  = (const float*)d_in[17];
    const float* core_n_W1  = (const float*)d_in[18];
    const float* core_n_b1  = (const float*)d_in[19];
    const float* dec_W0     = (const float*)d_in[20];
    const float* dec_b0     = (const float*)d_in[21];
    const float* dec_W1     = (const float*)d_in[22];
    const float* dec_b1     = (const float*)d_in[23];
    (void)n_in; (void)out_size;

    const int E = in_sizes[0] / 2;
    const int N = in_sizes[1] / 32;
    const int* src = edge_index;
    const int* dst = edge_index + E;

    auto al = [](size_t x) { return (x + 255) & ~(size_t)255; };
    const size_t szEdgeT = al((size_t)E * 64 * 4);
    const size_t szNodeT = al((size_t)N * 64 * 4);
    const size_t szP     = al((size_t)N * 128 * 4);
    const size_t szAgg   = al((size_t)N * 64 * 4);
    const size_t szElist = al((size_t)E * 4);
    const size_t szN4    = al((size_t)N * 4);
    const size_t szRow   = al((size_t)(N + 1) * 4);
    const size_t szEmbW  = al(2 * 128 * 4);
    const size_t needCommon = szEdgeT + szNodeT + szElist + szRow + 3 * szN4 + szEmbW;
    const size_t needA = needCommon + 2 * szP;
    const bool planA = ws_size >= needA;

    char* ws = (char*)d_ws;
    size_t off = 0;
    auto carve = [&](size_t bytes) -> char* { char* p = ws + off; off += bytes; return p; };
    float* edgeT   = (float*)carve(szEdgeT);
    float* nodeT   = (float*)carve(szNodeT);
    int*   elist   = (int*)  carve(szElist);
    int*   row_off = (int*)  carve(szRow);
    int*   counts  = (int*)  carve(szN4);
    int*   cursor  = (int*)  carve(szN4);
    float* inv_cnt = (float*)carve(szN4);
    float* embW    = (float*)carve(szEmbW);
    float* Pd = nullptr, *Ps = nullptr, *aggT = nullptr;
    if (planA) {
        Pd   = (float*)carve(szP);
        Ps   = (float*)carve(szP);
        aggT = Pd;                    // lifetime-disjoint alias
    } else {
        aggT = (float*)carve(szAgg);
    }

    int blkE = (E + 255) / 256;
    int blkN = (N + 255) / 256;

    k_zero<<<(N + 255) / 256, 256, 0, stream>>>(counts, N);
    k_hist<<<blkE, 256, 0, stream>>>(dst, counts, E);
    k_scan<<<1, 1024, 0, stream>>>(counts, row_off, cursor, inv_cnt, N);
    k_fill<<<blkE, 256, 0, stream>>>(dst, cursor, elist, E);

    k_embW<<<1, 128, 0, stream>>>(emb, enc_n_W0, enc_n_b0, embW);
    k_enc_node_tail<<<blkN, 256, 0, stream>>>(nodeF, embW, enc_n_W0, enc_n_W1,
                                              enc_n_b1, nodeT, N);
    k_enc_edge<<<blkE, 256, 0, stream>>>(edgeF, enc_e_W0, enc_e_b0, enc_e_W1,
                                         enc_e_b1, edgeT, E);

    for (int step = 0; step < 3; step++) {
        if (planA) {
            k_node_pre<<<blkN, 256, 0, stream>>>(nodeT, core_e_W0, core_e_b0, Pd, Ps, N);
            k_edge_core_A<<<blkE, 256, 0, stream>>>(edgeT, Pd, Ps, src, dst,
                                                    core_e_W0, core_e_W1, core_e_b1, E);
        } else {
            k_edge_core_B<<<blkE, 256, 0, stream>>>(edgeT, nodeT, src, dst,
                                                    core_e_W0, core_e_b0,
                                                    core_e_W1, core_e_b1, E);
        }
        k_agg<<<(N + 3) / 4, 256, 0, stream>>>(edgeT, row_off, elist, inv_cnt, aggT, N);
        k_node_core<<<blkN, 256, 0, stream>>>(aggT, nodeT, core_n_W0, core_n_b0,
                                              core_n_W1, core_n_b1, N);
    }
    k_decode<<<blkN, 256, 0, stream>>>(nodeF, embW, enc_n_W0, enc_n_W1, enc_n_b1,
                                       nodeT, dec_W0, dec_b0, dec_W1, dec_b1,
                                       (float*)d_out, N);
}

// Round 4
// 4582.841 us; speedup vs baseline: 1.0918x; 1.0918x over previous
//
#include <hip/hip_runtime.h>
#include <cstdint>
#include <cstddef>

// ---------------------------------------------------------------------------
// EncodeProcessDecode GNN, fp32.
// c-chunked register-tile MLPs; GEMM2 bounces h-chunks through per-thread LDS
// columns (conflict-free) so k-loops stay dynamic (small code, no spills).
// R4: __launch_bounds__(256,2) on GEMM kernels (R3's (256,3) capped VGPRs at
// ~170 -> compiler spilled o[64]/h[32], VGPR_Count=64, 3.0 GB scratch traffic
// per edge-core dispatch). Plan tiers by ws_size:
//   A  (~273 MB): Pd+Ps precomputed, edge = 32.8k FLOP
//   A' (~247 MB): Pd only + inline src gather, edge = 49.2k FLOP
//   B  (~234 MB): all inline, edge = 65.5k FLOP
// fp64 aggregation -> order-invariant under atomic CSR fill nondeterminism.
// ---------------------------------------------------------------------------

__global__ void k_zero(int* __restrict__ p, int n) {
    int i = blockIdx.x * 256 + threadIdx.x;
    if (i < n) p[i] = 0;
}

// ---------------- CSR build ----------------

__global__ void k_hist(const int* __restrict__ dst, int* __restrict__ counts, int E) {
    int e = blockIdx.x * 256 + threadIdx.x;
    if (e < E) atomicAdd(&counts[dst[e]], 1);
}

__global__ __launch_bounds__(1024) void k_scan(
    const int* __restrict__ counts, int* __restrict__ row_off,
    int* __restrict__ cursor, float* __restrict__ inv_cnt, int N) {
    __shared__ int wsum[16];
    int t = threadIdx.x;
    int wave = t >> 6, lane = t & 63;
    int carry = 0;
    for (int base = 0; base < N; base += 1024) {
        int i = base + t;
        int v = (i < N) ? counts[i] : 0;
        int s = v;
        #pragma unroll
        for (int off = 1; off < 64; off <<= 1) {
            int u = __shfl_up(s, off, 64);
            if (lane >= off) s += u;
        }
        if (lane == 63) wsum[wave] = s;
        __syncthreads();
        int wpre = 0, full = 0;
        #pragma unroll
        for (int wv = 0; wv < 16; wv++) {
            int x = wsum[wv];
            full += x;
            if (wv < wave) wpre += x;
        }
        if (i < N) {
            int excl = carry + wpre + s - v;
            row_off[i] = excl;
            cursor[i]  = excl;
            inv_cnt[i] = 1.0f / (float)((v > 0) ? v : 1);
        }
        carry += full;
        __syncthreads();
    }
    if (t == 0) row_off[N] = carry;
}

__global__ void k_fill(const int* __restrict__ dst, int* __restrict__ cursor,
                       int* __restrict__ edge_list, int E) {
    int e = blockIdx.x * 256 + threadIdx.x;
    if (e < E) {
        int pos = atomicAdd(&cursor[dst[e]], 1);
        edge_list[pos] = e;
    }
}

// ---------------- encoder helper table ----------------

__global__ void k_embW(const float* __restrict__ emb, const float* __restrict__ W0,
                       const float* __restrict__ b0, float* __restrict__ embW) {
    int c = threadIdx.x;  // 128 threads
    #pragma unroll
    for (int p = 0; p < 2; p++) {
        float acc = b0[c];
        #pragma unroll
        for (int k = 0; k < 16; k++)
            acc = fmaf(emb[p * 16 + k], W0[(31 + k) * 128 + c], acc);
        embW[p * 128 + c] = acc;
    }
}

// ---------------- GEMM building blocks ----------------

// h[0..31] += a[0..4*kk4) @ W[0..4*kk4)][cbase..cbase+32)   (W rows 128 wide)
__device__ __forceinline__ void g1_accum32(
    const float4* __restrict__ a4, int kk4,
    const float* __restrict__ W, int cbase, float* __restrict__ h) {
    #pragma clang loop unroll(disable)
    for (int kk = 0; kk < kk4; kk++) {
        float4 a = a4[kk];
        const float* wr = W + (size_t)kk * 4 * 128 + cbase;
        const float4* w0 = reinterpret_cast<const float4*>(wr);
        const float4* w1 = reinterpret_cast<const float4*>(wr + 128);
        const float4* w2 = reinterpret_cast<const float4*>(wr + 256);
        const float4* w3 = reinterpret_cast<const float4*>(wr + 384);
        #pragma unroll
        for (int cg = 0; cg < 8; cg++) {
            float4 p = w0[cg], q = w1[cg], r = w2[cg], s = w3[cg];
            h[cg*4+0] = fmaf(a.w, s.x, fmaf(a.z, r.x, fmaf(a.y, q.x, fmaf(a.x, p.x, h[cg*4+0]))));
            h[cg*4+1] = fmaf(a.w, s.y, fmaf(a.z, r.y, fmaf(a.y, q.y, fmaf(a.x, p.y, h[cg*4+1]))));
            h[cg*4+2] = fmaf(a.w, s.z, fmaf(a.z, r.z, fmaf(a.y, q.z, fmaf(a.x, p.z, h[cg*4+2]))));
            h[cg*4+3] = fmaf(a.w, s.w, fmaf(a.z, r.w, fmaf(a.y, q.w, fmaf(a.x, p.w, h[cg*4+3]))));
        }
    }
}

// h[0..31] += x*W[0][c..] + y*W[1][c..] + z*W[2][c..]
__device__ __forceinline__ void g1_tail3(
    float x, float y, float z, const float* __restrict__ W, int cbase,
    float* __restrict__ h) {
    const float4* w0 = reinterpret_cast<const float4*>(W + cbase);
    const float4* w1 = reinterpret_cast<const float4*>(W + 128 + cbase);
    const float4* w2 = reinterpret_cast<const float4*>(W + 256 + cbase);
    #pragma unroll
    for (int cg = 0; cg < 8; cg++) {
        float4 p = w0[cg], q = w1[cg], r = w2[cg];
        h[cg*4+0] = fmaf(z, r.x, fmaf(y, q.x, fmaf(x, p.x, h[cg*4+0])));
        h[cg*4+1] = fmaf(z, r.y, fmaf(y, q.y, fmaf(x, p.y, h[cg*4+1])));
        h[cg*4+2] = fmaf(z, r.z, fmaf(y, q.z, fmaf(x, p.z, h[cg*4+2])));
        h[cg*4+3] = fmaf(z, r.w, fmaf(y, q.w, fmaf(x, p.w, h[cg*4+3])));
    }
}

// o[0..64) += hc[0..32) @ W1[kbase..kbase+32)][0..64)  (row stride rs floats)
__device__ __forceinline__ void g2_accum64(
    float* __restrict__ sb, const float* __restrict__ hc,
    const float* __restrict__ W1, int kbase, int rs, float* __restrict__ o) {
    int t = threadIdx.x;
    #pragma unroll
    for (int k = 0; k < 32; k++) sb[k * 256 + t] = hc[k];
    __syncthreads();
    #pragma clang loop unroll(disable)
    for (int k = 0; k < 32; k++) {
        float hk = sb[k * 256 + t];
        const float4* w = reinterpret_cast<const float4*>(W1 + (size_t)(kbase + k) * rs);
        #pragma unroll
        for (int cg = 0; cg < 16; cg++) {
            float4 wv = w[cg];
            o[cg*4+0] = fmaf(hk, wv.x, o[cg*4+0]);
            o[cg*4+1] = fmaf(hk, wv.y, o[cg*4+1]);
            o[cg*4+2] = fmaf(hk, wv.z, o[cg*4+2]);
            o[cg*4+3] = fmaf(hk, wv.w, o[cg*4+3]);
        }
    }
    __syncthreads();
}

// ---------------- node encoder (tail only) ----------------

__global__ __launch_bounds__(256, 2) void k_enc_node_tail(
    const float* __restrict__ nodeF, const float* __restrict__ embW,
    const float* __restrict__ W0, const float* __restrict__ W1,
    const float* __restrict__ b1, float* __restrict__ nodeT, int N) {
    __shared__ float sb[32 * 256];
    int n = blockIdx.x * 256 + threadIdx.x;
    bool valid = n < N;
    int nc = valid ? n : N - 1;
    const float4* nf4 = reinterpret_cast<const float4*>(nodeF + (size_t)nc * 32);
    float4 v7 = nf4[7];
    int p = (int)(v7.w + 0.5f);
    const float4* ew = reinterpret_cast<const float4*>(embW + p * 128);

    float o[64];
    const float4* bv = reinterpret_cast<const float4*>(b1 + 64);
    #pragma unroll
    for (int i = 0; i < 16; i++) {
        float4 b = bv[i];
        o[4*i+0] = b.x; o[4*i+1] = b.y; o[4*i+2] = b.z; o[4*i+3] = b.w;
    }
    #pragma unroll
    for (int ch = 0; ch < 4; ch++) {
        int cbase = ch * 32;
        float h[32];
        #pragma unroll
        for (int i = 0; i < 8; i++) {
            float4 u = ew[ch*8 + i];
            h[4*i+0] = u.x; h[4*i+1] = u.y; h[4*i+2] = u.z; h[4*i+3] = u.w;
        }
        g1_accum32(nf4, 7, W0, cbase, h);
        g1_tail3(v7.x, v7.y, v7.z, W0 + 28*128, cbase, h);
        #pragma unroll
        for (int i = 0; i < 32; i++) h[i] = fmaxf(h[i], 0.0f);
        g2_accum64(sb, h, W1 + 64, cbase, 128, o);
    }
    if (valid) {
        float4* out4 = reinterpret_cast<float4*>(nodeT + (size_t)n * 64);
        #pragma unroll
        for (int i = 0; i < 16; i++)
            out4[i] = make_float4(o[4*i], o[4*i+1], o[4*i+2], o[4*i+3]);
    }
}

// ---------------- edge encoder ----------------

__global__ __launch_bounds__(256, 2) void k_enc_edge(
    const float* __restrict__ edgeF,
    const float* __restrict__ W0, const float* __restrict__ b0,
    const float* __restrict__ W1, const float* __restrict__ b1,
    float* __restrict__ edgeT, int E) {
    __shared__ float sb[32 * 256];
    int e = blockIdx.x * 256 + threadIdx.x;
    bool valid = e < E;
    int ec = valid ? e : E - 1;
    float x0 = edgeF[(size_t)ec * 3 + 0];
    float x1 = edgeF[(size_t)ec * 3 + 1];
    float x2 = edgeF[(size_t)ec * 3 + 2];

    float o[64];
    const float4* bv = reinterpret_cast<const float4*>(b1 + 64);
    #pragma unroll
    for (int i = 0; i < 16; i++) {
        float4 b = bv[i];
        o[4*i+0] = b.x; o[4*i+1] = b.y; o[4*i+2] = b.z; o[4*i+3] = b.w;
    }
    #pragma unroll
    for (int ch = 0; ch < 4; ch++) {
        int cbase = ch * 32;
        float h[32];
        const float4* b0v = reinterpret_cast<const float4*>(b0 + cbase);
        #pragma unroll
        for (int i = 0; i < 8; i++) {
            float4 b = b0v[i];
            h[4*i+0] = b.x; h[4*i+1] = b.y; h[4*i+2] = b.z; h[4*i+3] = b.w;
        }
        g1_tail3(x0, x1, x2, W0, cbase, h);
        #pragma unroll
        for (int i = 0; i < 32; i++) h[i] = fmaxf(h[i], 0.0f);
        g2_accum64(sb, h, W1 + 64, cbase, 128, o);
    }
    if (valid) {
        float4* out4 = reinterpret_cast<float4*>(edgeT + (size_t)e * 64);
        #pragma unroll
        for (int i = 0; i < 16; i++)
            out4[i] = make_float4(o[4*i], o[4*i+1], o[4*i+2], o[4*i+3]);
    }
}

// ------------- per-step node projections ------------------------------------

// Pd + Ps (plan A)
__global__ __launch_bounds__(256, 4) void k_node_pre(
    const float* __restrict__ nodeT, const float* __restrict__ W0,
    const float* __restrict__ b0,
    float* __restrict__ Pd, float* __restrict__ Ps, int N) {
    int n = blockIdx.x * 256 + threadIdx.x;
    bool valid = n < N;
    int nc = valid ? n : N - 1;
    const float4* a4 = reinterpret_cast<const float4*>(nodeT + (size_t)nc * 64);

    #pragma unroll
    for (int ch = 0; ch < 4; ch++) {
        int cbase = ch * 32;
        float h[32];
        const float4* b0v = reinterpret_cast<const float4*>(b0 + cbase);
        #pragma unroll
        for (int i = 0; i < 8; i++) {
            float4 b = b0v[i];
            h[4*i+0] = b.x; h[4*i+1] = b.y; h[4*i+2] = b.z; h[4*i+3] = b.w;
        }
        g1_accum32(a4, 16, W0 + 64*128, cbase, h);
        if (valid) {
            float4* o4 = reinterpret_cast<float4*>(Pd + (size_t)n * 128 + cbase);
            #pragma unroll
            for (int i = 0; i < 8; i++)
                o4[i] = make_float4(h[4*i], h[4*i+1], h[4*i+2], h[4*i+3]);
        }
    }
    #pragma unroll
    for (int ch = 0; ch < 4; ch++) {
        int cbase = ch * 32;
        float h[32];
        #pragma unroll
        for (int i = 0; i < 32; i++) h[i] = 0.0f;
        g1_accum32(a4, 16, W0 + 128*128, cbase, h);
        if (valid) {
            float4* o4 = reinterpret_cast<float4*>(Ps + (size_t)n * 128 + cbase);
            #pragma unroll
            for (int i = 0; i < 8; i++)
                o4[i] = make_float4(h[4*i], h[4*i+1], h[4*i+2], h[4*i+3]);
        }
    }
}

// Pd only (plan A')
__global__ __launch_bounds__(256, 4) void k_node_pre_d(
    const float* __restrict__ nodeT, const float* __restrict__ W0,
    const float* __restrict__ b0, float* __restrict__ Pd, int N) {
    int n = blockIdx.x * 256 + threadIdx.x;
    bool valid = n < N;
    int nc = valid ? n : N - 1;
    const float4* a4 = reinterpret_cast<const float4*>(nodeT + (size_t)nc * 64);

    #pragma unroll
    for (int ch = 0; ch < 4; ch++) {
        int cbase = ch * 32;
        float h[32];
        const float4* b0v = reinterpret_cast<const float4*>(b0 + cbase);
        #pragma unroll
        for (int i = 0; i < 8; i++) {
            float4 b = b0v[i];
            h[4*i+0] = b.x; h[4*i+1] = b.y; h[4*i+2] = b.z; h[4*i+3] = b.w;
        }
        g1_accum32(a4, 16, W0 + 64*128, cbase, h);
        if (valid) {
            float4* o4 = reinterpret_cast<float4*>(Pd + (size_t)n * 128 + cbase);
            #pragma unroll
            for (int i = 0; i < 8; i++)
                o4[i] = make_float4(h[4*i], h[4*i+1], h[4*i+2], h[4*i+3]);
        }
    }
}

// ------------- edge cores ---------------------------------------------------

__global__ __launch_bounds__(256, 2) void k_edge_core_A(
    float* __restrict__ edgeT,
    const float* __restrict__ Pd, const float* __restrict__ Ps,
    const int* __restrict__ src, const int* __restrict__ dst,
    const float* __restrict__ W0, const float* __restrict__ W1,
    const float* __restrict__ b1, int E) {
    __shared__ float sb[32 * 256];
    int e = blockIdx.x * 256 + threadIdx.x;
    bool valid = e < E;
    int ec = valid ? e : E - 1;
    int d = dst[ec], s = src[ec];
    const float4* a4  = reinterpret_cast<const float4*>(edgeT + (size_t)ec * 64);
    const float4* pd4 = reinterpret_cast<const float4*>(Pd + (size_t)d * 128);
    const float4* ps4 = reinterpret_cast<const float4*>(Ps + (size_t)s * 128);

    float o[64];
    const float4* bv = reinterpret_cast<const float4*>(b1);
    #pragma unroll
    for (int i = 0; i < 16; i++) {
        float4 b = bv[i];
        o[4*i+0] = b.x; o[4*i+1] = b.y; o[4*i+2] = b.z; o[4*i+3] = b.w;
    }
    #pragma unroll
    for (int ch = 0; ch < 4; ch++) {
        int cbase = ch * 32;
        float h[32];
        #pragma unroll
        for (int i = 0; i < 8; i++) {
            float4 u = pd4[ch*8 + i];
            float4 v = ps4[ch*8 + i];
            h[4*i+0] = u.x + v.x; h[4*i+1] = u.y + v.y;
            h[4*i+2] = u.z + v.z; h[4*i+3] = u.w + v.w;
        }
        g1_accum32(a4, 16, W0, cbase, h);
        #pragma unroll
        for (int i = 0; i < 32; i++) h[i] = fmaxf(h[i], 0.0f);
        g2_accum64(sb, h, W1, cbase, 64, o);
    }
    if (valid) {
        float4* eo4 = reinterpret_cast<float4*>(edgeT + (size_t)e * 64);
        #pragma unroll
        for (int i = 0; i < 16; i++) {
            float4 t = a4[i];
            t.x += o[4*i+0]; t.y += o[4*i+1];
            t.z += o[4*i+2]; t.w += o[4*i+3];
            eo4[i] = t;
        }
    }
}

// plan A': h = Pd[dst] + edgeT@W0[0:64] + nodeT[src]@W0[128:192]
__global__ __launch_bounds__(256, 2) void k_edge_core_Ap(
    float* __restrict__ edgeT, const float* __restrict__ Pd,
    const float* __restrict__ nodeT,
    const int* __restrict__ src, const int* __restrict__ dst,
    const float* __restrict__ W0, const float* __restrict__ W1,
    const float* __restrict__ b1, int E) {
    __shared__ float sb[32 * 256];
    int e = blockIdx.x * 256 + threadIdx.x;
    bool valid = e < E;
    int ec = valid ? e : E - 1;
    int d = dst[ec], s = src[ec];
    const float4* a4  = reinterpret_cast<const float4*>(edgeT + (size_t)ec * 64);
    const float4* s4  = reinterpret_cast<const float4*>(nodeT + (size_t)s * 64);
    const float4* pd4 = reinterpret_cast<const float4*>(Pd + (size_t)d * 128);

    float o[64];
    const float4* bv = reinterpret_cast<const float4*>(b1);
    #pragma unroll
    for (int i = 0; i < 16; i++) {
        float4 b = bv[i];
        o[4*i+0] = b.x; o[4*i+1] = b.y; o[4*i+2] = b.z; o[4*i+3] = b.w;
    }
    #pragma unroll
    for (int ch = 0; ch < 4; ch++) {
        int cbase = ch * 32;
        float h[32];
        #pragma unroll
        for (int i = 0; i < 8; i++) {
            float4 u = pd4[ch*8 + i];
            h[4*i+0] = u.x; h[4*i+1] = u.y; h[4*i+2] = u.z; h[4*i+3] = u.w;
        }
        g1_accum32(a4, 16, W0, cbase, h);
        g1_accum32(s4, 16, W0 + 128*128, cbase, h);
        #pragma unroll
        for (int i = 0; i < 32; i++) h[i] = fmaxf(h[i], 0.0f);
        g2_accum64(sb, h, W1, cbase, 64, o);
    }
    if (valid) {
        float4* eo4 = reinterpret_cast<float4*>(edgeT + (size_t)e * 64);
        #pragma unroll
        for (int i = 0; i < 16; i++) {
            float4 t = a4[i];
            t.x += o[4*i+0]; t.y += o[4*i+1];
            t.z += o[4*i+2]; t.w += o[4*i+3];
            eo4[i] = t;
        }
    }
}

__global__ __launch_bounds__(256, 2) void k_edge_core_B(
    float* __restrict__ edgeT, const float* __restrict__ nodeT,
    const int* __restrict__ src, const int* __restrict__ dst,
    const float* __restrict__ W0, const float* __restrict__ b0,
    const float* __restrict__ W1, const float* __restrict__ b1, int E) {
    __shared__ float sb[32 * 256];
    int e = blockIdx.x * 256 + threadIdx.x;
    bool valid = e < E;
    int ec = valid ? e : E - 1;
    int d = dst[ec], s = src[ec];
    const float4* a4 = reinterpret_cast<const float4*>(edgeT + (size_t)ec * 64);
    const float4* d4 = reinterpret_cast<const float4*>(nodeT + (size_t)d * 64);
    const float4* s4 = reinterpret_cast<const float4*>(nodeT + (size_t)s * 64);

    float o[64];
    const float4* bv = reinterpret_cast<const float4*>(b1);
    #pragma unroll
    for (int i = 0; i < 16; i++) {
        float4 b = bv[i];
        o[4*i+0] = b.x; o[4*i+1] = b.y; o[4*i+2] = b.z; o[4*i+3] = b.w;
    }
    #pragma unroll
    for (int ch = 0; ch < 4; ch++) {
        int cbase = ch * 32;
        float h[32];
        const float4* b0v = reinterpret_cast<const float4*>(b0 + cbase);
        #pragma unroll
        for (int i = 0; i < 8; i++) {
            float4 b = b0v[i];
            h[4*i+0] = b.x; h[4*i+1] = b.y; h[4*i+2] = b.z; h[4*i+3] = b.w;
        }
        g1_accum32(a4, 16, W0, cbase, h);
        g1_accum32(d4, 16, W0 + 64*128, cbase, h);
        g1_accum32(s4, 16, W0 + 128*128, cbase, h);
        #pragma unroll
        for (int i = 0; i < 32; i++) h[i] = fmaxf(h[i], 0.0f);
        g2_accum64(sb, h, W1, cbase, 64, o);
    }
    if (valid) {
        float4* eo4 = reinterpret_cast<float4*>(edgeT + (size_t)e * 64);
        #pragma unroll
        for (int i = 0; i < 16; i++) {
            float4 t = a4[i];
            t.x += o[4*i+0]; t.y += o[4*i+1];
            t.z += o[4*i+2]; t.w += o[4*i+3];
            eo4[i] = t;
        }
    }
}

// ------------- mean aggregation (fp64 accumulate -> order-invariant) --------

__global__ __launch_bounds__(256) void k_agg(
    const float* __restrict__ edgeT, const int* __restrict__ row_off,
    const int* __restrict__ edge_list, const float* __restrict__ inv_cnt,
    float* __restrict__ aggT, int N) {
    int n = blockIdx.x * 4 + (threadIdx.x >> 6);
    int lane = threadIdx.x & 63;
    if (n >= N) return;
    int beg = row_off[n], end = row_off[n + 1];
    double s = 0.0;
    for (int idx = beg; idx < end; idx++) {
        int e = edge_list[idx];
        s += (double)edgeT[(size_t)e * 64 + lane];
    }
    aggT[(size_t)n * 64 + lane] = (float)(s * (double)inv_cnt[n]);
}

// ------------- node core ----------------------------------------------------

__global__ __launch_bounds__(256, 2) void k_node_core(
    const float* __restrict__ aggT, float* __restrict__ nodeT,
    const float* __restrict__ W0, const float* __restrict__ b0,
    const float* __restrict__ W1, const float* __restrict__ b1, int N) {
    __shared__ float sb[32 * 256];
    int n = blockIdx.x * 256 + threadIdx.x;
    bool valid = n < N;
    int nc = valid ? n : N - 1;
    const float4* g4 = reinterpret_cast<const float4*>(aggT + (size_t)nc * 64);
    const float4* t4 = reinterpret_cast<const float4*>(nodeT + (size_t)nc * 64);

    float o[64];
    const float4* bv = reinterpret_cast<const float4*>(b1);
    #pragma unroll
    for (int i = 0; i < 16; i++) {
        float4 b = bv[i];
        o[4*i+0] = b.x; o[4*i+1] = b.y; o[4*i+2] = b.z; o[4*i+3] = b.w;
    }
    #pragma unroll
    for (int ch = 0; ch < 4; ch++) {
        int cbase = ch * 32;
        float h[32];
        const float4* b0v = reinterpret_cast<const float4*>(b0 + cbase);
        #pragma unroll
        for (int i = 0; i < 8; i++) {
            float4 b = b0v[i];
            h[4*i+0] = b.x; h[4*i+1] = b.y; h[4*i+2] = b.z; h[4*i+3] = b.w;
        }
        g1_accum32(g4, 16, W0, cbase, h);
        g1_accum32(t4, 16, W0 + 64*128, cbase, h);
        #pragma unroll
        for (int i = 0; i < 32; i++) h[i] = fmaxf(h[i], 0.0f);
        g2_accum64(sb, h, W1, cbase, 64, o);
    }
    if (valid) {
        float4* nt4 = reinterpret_cast<float4*>(nodeT + (size_t)n * 64);
        #pragma unroll
        for (int i = 0; i < 16; i++) {
            float4 t = t4[i];
            t.x += o[4*i+0]; t.y += o[4*i+1];
            t.z += o[4*i+2]; t.w += o[4*i+3];
            nt4[i] = t;
        }
    }
}

// ------------- decoder (recomputes encoder head) ----------------------------

__global__ __launch_bounds__(256, 2) void k_decode(
    const float* __restrict__ nodeF, const float* __restrict__ embW,
    const float* __restrict__ encW0, const float* __restrict__ encW1,
    const float* __restrict__ encb1, const float* __restrict__ nodeT,
    const float* __restrict__ W0, const float* __restrict__ b0,
    const float* __restrict__ W1, const float* __restrict__ b1,
    float* __restrict__ out, int N) {
    __shared__ float sb[64 * 256];
    int t = threadIdx.x;
    int n = blockIdx.x * 256 + t;
    bool valid = n < N;
    int nc = valid ? n : N - 1;
    const float4* nf4 = reinterpret_cast<const float4*>(nodeF + (size_t)nc * 32);
    const float4* t4  = reinterpret_cast<const float4*>(nodeT + (size_t)nc * 64);
    float4 v7 = nf4[7];
    int p = (int)(v7.w + 0.5f);
    const float4* ew = reinterpret_cast<const float4*>(embW + p * 128);

    float head[64];
    const float4* ebv = reinterpret_cast<const float4*>(encb1);
    #pragma unroll
    for (int i = 0; i < 16; i++) {
        float4 b = ebv[i];
        head[4*i+0] = b.x; head[4*i+1] = b.y; head[4*i+2] = b.z; head[4*i+3] = b.w;
    }
    #pragma unroll
    for (int ch = 0; ch < 4; ch++) {
        int cbase = ch * 32;
        float h[32];
        #pragma unroll
        for (int i = 0; i < 8; i++) {
            float4 u = ew[ch*8 + i];
            h[4*i+0] = u.x; h[4*i+1] = u.y; h[4*i+2] = u.z; h[4*i+3] = u.w;
        }
        g1_accum32(nf4, 7, encW0, cbase, h);
        g1_tail3(v7.x, v7.y, v7.z, encW0 + 28*128, cbase, h);
        #pragma unroll
        for (int i = 0; i < 32; i++) h[i] = fmaxf(h[i], 0.0f);
        g2_accum64(sb, h, encW1, cbase, 128, head);
    }

    #pragma unroll
    for (int k = 0; k < 64; k++) sb[k * 256 + t] = head[k];
    __syncthreads();

    float h2[128];
    #pragma unroll
    for (int ch = 0; ch < 4; ch++) {
        int cbase = ch * 32;
        float* hc = &h2[ch * 32];
        const float4* b0v = reinterpret_cast<const float4*>(b0 + cbase);
        #pragma unroll
        for (int i = 0; i < 8; i++) {
            float4 b = b0v[i];
            hc[4*i+0] = b.x; hc[4*i+1] = b.y; hc[4*i+2] = b.z; hc[4*i+3] = b.w;
        }
        #pragma clang loop unroll(disable)
        for (int k = 0; k < 64; k++) {
            float hk = sb[k * 256 + t];
            const float4* w = reinterpret_cast<const float4*>(W0 + (size_t)k * 128 + cbase);
            #pragma unroll
            for (int cg = 0; cg < 8; cg++) {
                float4 wv = w[cg];
                hc[cg*4+0] = fmaf(hk, wv.x, hc[cg*4+0]);
                hc[cg*4+1] = fmaf(hk, wv.y, hc[cg*4+1]);
                hc[cg*4+2] = fmaf(hk, wv.z, hc[cg*4+2]);
                hc[cg*4+3] = fmaf(hk, wv.w, hc[cg*4+3]);
            }
        }
        g1_accum32(t4, 16, W0 + 64*128, cbase, hc);
    }
    __syncthreads();

    float o0 = b1[0], o1 = b1[1], o2 = b1[2];
    #pragma unroll
    for (int ch = 0; ch < 4; ch++) {
        int kb = ch * 32;
        #pragma unroll
        for (int k = 0; k < 32; k++) sb[k * 256 + t] = fmaxf(h2[kb + k], 0.0f);
        __syncthreads();
        #pragma clang loop unroll(disable)
        for (int k = 0; k < 32; k++) {
            float hk = sb[k * 256 + t];
            const float* w = W1 + (size_t)(kb + k) * 3;
            o0 = fmaf(hk, w[0], o0);
            o1 = fmaf(hk, w[1], o1);
            o2 = fmaf(hk, w[2], o2);
        }
        __syncthreads();
    }
    if (valid) {
        out[(size_t)n * 3 + 0] = o0;
        out[(size_t)n * 3 + 1] = o1;
        out[(size_t)n * 3 + 2] = o2;
    }
}

// ---------------------------------------------------------------------------

extern "C" void kernel_launch(void* const* d_in, const int* in_sizes, int n_in,
                              void* d_out, int out_size, void* d_ws, size_t ws_size,
                              hipStream_t stream) {
    const int*   edge_index = (const int*)  d_in[0];
    const float* nodeF      = (const float*)d_in[1];
    const float* edgeF      = (const float*)d_in[2];
    const float* emb        = (const float*)d_in[3];
    const float* enc_n_W0   = (const float*)d_in[4];
    const float* enc_n_b0   = (const float*)d_in[5];
    const float* enc_n_W1   = (const float*)d_in[6];
    const float* enc_n_b1   = (const float*)d_in[7];
    const float* enc_e_W0   = (const float*)d_in[8];
    const float* enc_e_b0   = (const float*)d_in[9];
    const float* enc_e_W1   = (const float*)d_in[10];
    const float* enc_e_b1   = (const float*)d_in[11];
    const float* core_e_W0  = (const float*)d_in[12];
    const float* core_e_b0  = (const float*)d_in[13];
    const float* core_e_W1  = (const float*)d_in[14];
    const float* core_e_b1  = (const float*)d_in[15];
    const float* core_n_W0  = (const float*)d_in[16];
    const float* core_n_b0  = (const float*)d_in[17];
    const float* core_n_W1  = (const float*)d_in[18];
    const float* core_n_b1  = (const float*)d_in[19];
    const float* dec_W0     = (const float*)d_in[20];
    const float* dec_b0     = (const float*)d_in[21];
    const float* dec_W1     = (const float*)d_in[22];
    const float* dec_b1     = (const float*)d_in[23];
    (void)n_in; (void)out_size;

    const int E = in_sizes[0] / 2;
    const int N = in_sizes[1] / 32;
    const int* src = edge_index;
    const int* dst = edge_index + E;

    auto al = [](size_t x) { return (x + 255) & ~(size_t)255; };
    const size_t szEdgeT = al((size_t)E * 64 * 4);
    const size_t szNodeT = al((size_t)N * 64 * 4);
    const size_t szP     = al((size_t)N * 128 * 4);
    const size_t szAgg   = al((size_t)N * 64 * 4);
    const size_t szElist = al((size_t)E * 4);
    const size_t szN4    = al((size_t)N * 4);
    const size_t szRow   = al((size_t)(N + 1) * 4);
    const size_t szEmbW  = al(2 * 128 * 4);
    const size_t base = szEdgeT + szNodeT + szElist + szRow + 3 * szN4 + szEmbW;
    const size_t needA  = base + 2 * szP;   // Pd (aggT alias) + Ps
    const size_t needAp = base + szP;       // Pd (aggT alias)
    const int plan = (ws_size >= needA) ? 0 : (ws_size >= needAp) ? 1 : 2;

    char* ws = (char*)d_ws;
    size_t off = 0;
    auto carve = [&](size_t bytes) -> char* { char* p = ws + off; off += bytes; return p; };
    float* edgeT   = (float*)carve(szEdgeT);
    float* nodeT   = (float*)carve(szNodeT);
    int*   elist   = (int*)  carve(szElist);
    int*   row_off = (int*)  carve(szRow);
    int*   counts  = (int*)  carve(szN4);
    int*   cursor  = (int*)  carve(szN4);
    float* inv_cnt = (float*)carve(szN4);
    float* embW    = (float*)carve(szEmbW);
    float* Pd = nullptr, *Ps = nullptr, *aggT = nullptr;
    if (plan == 0) {
        Pd = (float*)carve(szP); Ps = (float*)carve(szP); aggT = Pd;
    } else if (plan == 1) {
        Pd = (float*)carve(szP); aggT = Pd;
    } else {
        aggT = (float*)carve(szAgg);
    }

    int blkE = (E + 255) / 256;
    int blkN = (N + 255) / 256;

    k_zero<<<(N + 255) / 256, 256, 0, stream>>>(counts, N);
    k_hist<<<blkE, 256, 0, stream>>>(dst, counts, E);
    k_scan<<<1, 1024, 0, stream>>>(counts, row_off, cursor, inv_cnt, N);
    k_fill<<<blkE, 256, 0, stream>>>(dst, cursor, elist, E);

    k_embW<<<1, 128, 0, stream>>>(emb, enc_n_W0, enc_n_b0, embW);
    k_enc_node_tail<<<blkN, 256, 0, stream>>>(nodeF, embW, enc_n_W0, enc_n_W1,
                                              enc_n_b1, nodeT, N);
    k_enc_edge<<<blkE, 256, 0, stream>>>(edgeF, enc_e_W0, enc_e_b0, enc_e_W1,
                                         enc_e_b1, edgeT, E);

    for (int step = 0; step < 3; step++) {
        if (plan == 0) {
            k_node_pre<<<blkN, 256, 0, stream>>>(nodeT, core_e_W0, core_e_b0, Pd, Ps, N);
            k_edge_core_A<<<blkE, 256, 0, stream>>>(edgeT, Pd, Ps, src, dst,
                                                    core_e_W0, core_e_W1, core_e_b1, E);
        } else if (plan == 1) {
            k_node_pre_d<<<blkN, 256, 0, stream>>>(nodeT, core_e_W0, core_e_b0, Pd, N);
            k_edge_core_Ap<<<blkE, 256, 0, stream>>>(edgeT, Pd, nodeT, src, dst,
                                                     core_e_W0, core_e_W1, core_e_b1, E);
        } else {
            k_edge_core_B<<<blkE, 256, 0, stream>>>(edgeT, nodeT, src, dst,
                                                    core_e_W0, core_e_b0,
                                                    core_e_W1, core_e_b1, E);
        }
        k_agg<<<(N + 3) / 4, 256, 0, stream>>>(edgeT, row_off, elist, inv_cnt, aggT, N);
        k_node_core<<<blkN, 256, 0, stream>>>(aggT, nodeT, core_n_W0, core_n_b0,
                                              core_n_W1, core_n_b1, N);
    }
    k_decode<<<blkN, 256, 0, stream>>>(nodeF, embW, enc_n_W0, enc_n_W1, enc_n_b1,
                                       nodeT, dec_W0, dec_b0, dec_W1, dec_b1,
                                       (float*)d_out, N);
}

// Round 5
// 3852.411 us; speedup vs baseline: 1.2988x; 1.1896x over previous
//
#include <hip/hip_runtime.h>
#include <cstdint>
#include <cstddef>

// ---------------------------------------------------------------------------
// EncodeProcessDecode GNN, fp32.
// R5: CSR-permuted edge state (edgeT stored dst-sorted) -> k_agg is fully
// streaming, Pd[dst] gathers are runs of equal dst (L1 broadcast), edgeT
// block tile stays L2-hot. Edge core uses 2x64-column chunks (was 4x32) to
// halve the nodeT[src] gather re-stream (R4 FETCH 2.7GB explained by 4x
// re-reading the 256B activation rows per chunk). GEMM2 bounces h-chunks
// through per-thread LDS columns (32KB, conflict-free). fp64 aggregation ->
// order-invariant under atomic CSR fill nondeterminism.
// Plan tiers by ws_size: 0 = CSR+Pd (253.6e6), 1 = A' non-CSR (247e6),
// 2 = B all-inline (234e6).
// ---------------------------------------------------------------------------

__global__ void k_zero(int* __restrict__ p, int n) {
    int i = blockIdx.x * 256 + threadIdx.x;
    if (i < n) p[i] = 0;
}

// ---------------- CSR build ----------------

__global__ void k_hist(const int* __restrict__ dst, int* __restrict__ counts, int E) {
    int e = blockIdx.x * 256 + threadIdx.x;
    if (e < E) atomicAdd(&counts[dst[e]], 1);
}

__global__ __launch_bounds__(1024) void k_scan(
    const int* __restrict__ counts, int* __restrict__ row_off,
    int* __restrict__ cursor, float* __restrict__ inv_cnt, int N) {
    __shared__ int wsum[16];
    int t = threadIdx.x;
    int wave = t >> 6, lane = t & 63;
    int carry = 0;
    for (int base = 0; base < N; base += 1024) {
        int i = base + t;
        int v = (i < N) ? counts[i] : 0;
        int s = v;
        #pragma unroll
        for (int off = 1; off < 64; off <<= 1) {
            int u = __shfl_up(s, off, 64);
            if (lane >= off) s += u;
        }
        if (lane == 63) wsum[wave] = s;
        __syncthreads();
        int wpre = 0, full = 0;
        #pragma unroll
        for (int wv = 0; wv < 16; wv++) {
            int x = wsum[wv];
            full += x;
            if (wv < wave) wpre += x;
        }
        if (i < N) {
            int excl = carry + wpre + s - v;
            row_off[i] = excl;
            cursor[i]  = excl;
            inv_cnt[i] = 1.0f / (float)((v > 0) ? v : 1);
        }
        carry += full;
        __syncthreads();
    }
    if (t == 0) row_off[N] = carry;
}

__global__ void k_fill(const int* __restrict__ dst, int* __restrict__ cursor,
                       int* __restrict__ edge_list, int E) {
    int e = blockIdx.x * 256 + threadIdx.x;
    if (e < E) {
        int pos = atomicAdd(&cursor[dst[e]], 1);
        edge_list[pos] = e;
    }
}

// src_p/dst_p in CSR position order
__global__ void k_perm_idx(const int* __restrict__ elist,
                           const int* __restrict__ src, const int* __restrict__ dst,
                           int* __restrict__ src_p, int* __restrict__ dst_p, int E) {
    int i = blockIdx.x * 256 + threadIdx.x;
    if (i < E) {
        int e = elist[i];
        src_p[i] = src[e];
        dst_p[i] = dst[e];
    }
}

// ---------------- encoder helper table ----------------

__global__ void k_embW(const float* __restrict__ emb, const float* __restrict__ W0,
                       const float* __restrict__ b0, float* __restrict__ embW) {
    int c = threadIdx.x;  // 128 threads
    #pragma unroll
    for (int p = 0; p < 2; p++) {
        float acc = b0[c];
        #pragma unroll
        for (int k = 0; k < 16; k++)
            acc = fmaf(emb[p * 16 + k], W0[(31 + k) * 128 + c], acc);
        embW[p * 128 + c] = acc;
    }
}

// ---------------- GEMM building blocks ----------------

// h[0..31] += a[0..4*kk4) @ W[.][cbase..cbase+32)   (W rows 128 wide)
__device__ __forceinline__ void g1_accum32(
    const float4* __restrict__ a4, int kk4,
    const float* __restrict__ W, int cbase, float* __restrict__ h) {
    #pragma clang loop unroll(disable)
    for (int kk = 0; kk < kk4; kk++) {
        float4 a = a4[kk];
        const float* wr = W + (size_t)kk * 4 * 128 + cbase;
        const float4* w0 = reinterpret_cast<const float4*>(wr);
        const float4* w1 = reinterpret_cast<const float4*>(wr + 128);
        const float4* w2 = reinterpret_cast<const float4*>(wr + 256);
        const float4* w3 = reinterpret_cast<const float4*>(wr + 384);
        #pragma unroll
        for (int cg = 0; cg < 8; cg++) {
            float4 p = w0[cg], q = w1[cg], r = w2[cg], s = w3[cg];
            h[cg*4+0] = fmaf(a.w, s.x, fmaf(a.z, r.x, fmaf(a.y, q.x, fmaf(a.x, p.x, h[cg*4+0]))));
            h[cg*4+1] = fmaf(a.w, s.y, fmaf(a.z, r.y, fmaf(a.y, q.y, fmaf(a.x, p.y, h[cg*4+1]))));
            h[cg*4+2] = fmaf(a.w, s.z, fmaf(a.z, r.z, fmaf(a.y, q.z, fmaf(a.x, p.z, h[cg*4+2]))));
            h[cg*4+3] = fmaf(a.w, s.w, fmaf(a.z, r.w, fmaf(a.y, q.w, fmaf(a.x, p.w, h[cg*4+3]))));
        }
    }
}

// 64-wide variant: h[0..63] += a @ W[.][cbase..cbase+64)
__device__ __forceinline__ void g1_accum64(
    const float4* __restrict__ a4, int kk4,
    const float* __restrict__ W, int cbase, float* __restrict__ h) {
    #pragma clang loop unroll(disable)
    for (int kk = 0; kk < kk4; kk++) {
        float4 a = a4[kk];
        const float* wr = W + (size_t)kk * 4 * 128 + cbase;
        const float4* w0 = reinterpret_cast<const float4*>(wr);
        const float4* w1 = reinterpret_cast<const float4*>(wr + 128);
        const float4* w2 = reinterpret_cast<const float4*>(wr + 256);
        const float4* w3 = reinterpret_cast<const float4*>(wr + 384);
        #pragma unroll
        for (int cg = 0; cg < 16; cg++) {
            float4 p = w0[cg], q = w1[cg], r = w2[cg], s = w3[cg];
            h[cg*4+0] = fmaf(a.w, s.x, fmaf(a.z, r.x, fmaf(a.y, q.x, fmaf(a.x, p.x, h[cg*4+0]))));
            h[cg*4+1] = fmaf(a.w, s.y, fmaf(a.z, r.y, fmaf(a.y, q.y, fmaf(a.x, p.y, h[cg*4+1]))));
            h[cg*4+2] = fmaf(a.w, s.z, fmaf(a.z, r.z, fmaf(a.y, q.z, fmaf(a.x, p.z, h[cg*4+2]))));
            h[cg*4+3] = fmaf(a.w, s.w, fmaf(a.z, r.w, fmaf(a.y, q.w, fmaf(a.x, p.w, h[cg*4+3]))));
        }
    }
}

// h[0..31] += x*W[0][c..] + y*W[1][c..] + z*W[2][c..]
__device__ __forceinline__ void g1_tail3(
    float x, float y, float z, const float* __restrict__ W, int cbase,
    float* __restrict__ h) {
    const float4* w0 = reinterpret_cast<const float4*>(W + cbase);
    const float4* w1 = reinterpret_cast<const float4*>(W + 128 + cbase);
    const float4* w2 = reinterpret_cast<const float4*>(W + 256 + cbase);
    #pragma unroll
    for (int cg = 0; cg < 8; cg++) {
        float4 p = w0[cg], q = w1[cg], r = w2[cg];
        h[cg*4+0] = fmaf(z, r.x, fmaf(y, q.x, fmaf(x, p.x, h[cg*4+0])));
        h[cg*4+1] = fmaf(z, r.y, fmaf(y, q.y, fmaf(x, p.y, h[cg*4+1])));
        h[cg*4+2] = fmaf(z, r.z, fmaf(y, q.z, fmaf(x, p.z, h[cg*4+2])));
        h[cg*4+3] = fmaf(z, r.w, fmaf(y, q.w, fmaf(x, p.w, h[cg*4+3])));
    }
}

// o[0..64) += hc[0..32) @ W1[kbase..kbase+32)][0..64)  (row stride rs floats)
__device__ __forceinline__ void g2_accum64(
    float* __restrict__ sb, const float* __restrict__ hc,
    const float* __restrict__ W1, int kbase, int rs, float* __restrict__ o) {
    int t = threadIdx.x;
    #pragma unroll
    for (int k = 0; k < 32; k++) sb[k * 256 + t] = hc[k];
    __syncthreads();
    #pragma clang loop unroll(disable)
    for (int k = 0; k < 32; k++) {
        float hk = sb[k * 256 + t];
        const float4* w = reinterpret_cast<const float4*>(W1 + (size_t)(kbase + k) * rs);
        #pragma unroll
        for (int cg = 0; cg < 16; cg++) {
            float4 wv = w[cg];
            o[cg*4+0] = fmaf(hk, wv.x, o[cg*4+0]);
            o[cg*4+1] = fmaf(hk, wv.y, o[cg*4+1]);
            o[cg*4+2] = fmaf(hk, wv.z, o[cg*4+2]);
            o[cg*4+3] = fmaf(hk, wv.w, o[cg*4+3]);
        }
    }
    __syncthreads();
}

// ---------------- node encoder (tail only) ----------------

__global__ __launch_bounds__(256, 2) void k_enc_node_tail(
    const float* __restrict__ nodeF, const float* __restrict__ embW,
    const float* __restrict__ W0, const float* __restrict__ W1,
    const float* __restrict__ b1, float* __restrict__ nodeT, int N) {
    __shared__ float sb[32 * 256];
    int n = blockIdx.x * 256 + threadIdx.x;
    bool valid = n < N;
    int nc = valid ? n : N - 1;
    const float4* nf4 = reinterpret_cast<const float4*>(nodeF + (size_t)nc * 32);
    float4 v7 = nf4[7];
    int p = (int)(v7.w + 0.5f);
    const float4* ew = reinterpret_cast<const float4*>(embW + p * 128);

    float o[64];
    const float4* bv = reinterpret_cast<const float4*>(b1 + 64);
    #pragma unroll
    for (int i = 0; i < 16; i++) {
        float4 b = bv[i];
        o[4*i+0] = b.x; o[4*i+1] = b.y; o[4*i+2] = b.z; o[4*i+3] = b.w;
    }
    #pragma unroll
    for (int ch = 0; ch < 4; ch++) {
        int cbase = ch * 32;
        float h[32];
        #pragma unroll
        for (int i = 0; i < 8; i++) {
            float4 u = ew[ch*8 + i];
            h[4*i+0] = u.x; h[4*i+1] = u.y; h[4*i+2] = u.z; h[4*i+3] = u.w;
        }
        g1_accum32(nf4, 7, W0, cbase, h);
        g1_tail3(v7.x, v7.y, v7.z, W0 + 28*128, cbase, h);
        #pragma unroll
        for (int i = 0; i < 32; i++) h[i] = fmaxf(h[i], 0.0f);
        g2_accum64(sb, h, W1 + 64, cbase, 128, o);
    }
    if (valid) {
        float4* out4 = reinterpret_cast<float4*>(nodeT + (size_t)n * 64);
        #pragma unroll
        for (int i = 0; i < 16; i++)
            out4[i] = make_float4(o[4*i], o[4*i+1], o[4*i+2], o[4*i+3]);
    }
}

// ---------------- edge encoder (optional input permutation) -----------------

__global__ __launch_bounds__(256, 2) void k_enc_edge(
    const float* __restrict__ edgeF, const int* __restrict__ perm, int usePerm,
    const float* __restrict__ W0, const float* __restrict__ b0,
    const float* __restrict__ W1, const float* __restrict__ b1,
    float* __restrict__ edgeT, int E) {
    __shared__ float sb[32 * 256];
    int e = blockIdx.x * 256 + threadIdx.x;
    bool valid = e < E;
    int ec = valid ? e : E - 1;
    int e2 = usePerm ? perm[ec] : ec;
    float x0 = edgeF[(size_t)e2 * 3 + 0];
    float x1 = edgeF[(size_t)e2 * 3 + 1];
    float x2 = edgeF[(size_t)e2 * 3 + 2];

    float o[64];
    const float4* bv = reinterpret_cast<const float4*>(b1 + 64);
    #pragma unroll
    for (int i = 0; i < 16; i++) {
        float4 b = bv[i];
        o[4*i+0] = b.x; o[4*i+1] = b.y; o[4*i+2] = b.z; o[4*i+3] = b.w;
    }
    #pragma unroll
    for (int ch = 0; ch < 4; ch++) {
        int cbase = ch * 32;
        float h[32];
        const float4* b0v = reinterpret_cast<const float4*>(b0 + cbase);
        #pragma unroll
        for (int i = 0; i < 8; i++) {
            float4 b = b0v[i];
            h[4*i+0] = b.x; h[4*i+1] = b.y; h[4*i+2] = b.z; h[4*i+3] = b.w;
        }
        g1_tail3(x0, x1, x2, W0, cbase, h);
        #pragma unroll
        for (int i = 0; i < 32; i++) h[i] = fmaxf(h[i], 0.0f);
        g2_accum64(sb, h, W1 + 64, cbase, 128, o);
    }
    if (valid) {
        float4* out4 = reinterpret_cast<float4*>(edgeT + (size_t)e * 64);
        #pragma unroll
        for (int i = 0; i < 16; i++)
            out4[i] = make_float4(o[4*i], o[4*i+1], o[4*i+2], o[4*i+3]);
    }
}

// ------------- per-step node projection (Pd only) ---------------------------

__global__ __launch_bounds__(256, 4) void k_node_pre_d(
    const float* __restrict__ nodeT, const float* __restrict__ W0,
    const float* __restrict__ b0, float* __restrict__ Pd, int N) {
    int n = blockIdx.x * 256 + threadIdx.x;
    bool valid = n < N;
    int nc = valid ? n : N - 1;
    const float4* a4 = reinterpret_cast<const float4*>(nodeT + (size_t)nc * 64);

    #pragma unroll
    for (int ch = 0; ch < 4; ch++) {
        int cbase = ch * 32;
        float h[32];
        const float4* b0v = reinterpret_cast<const float4*>(b0 + cbase);
        #pragma unroll
        for (int i = 0; i < 8; i++) {
            float4 b = b0v[i];
            h[4*i+0] = b.x; h[4*i+1] = b.y; h[4*i+2] = b.z; h[4*i+3] = b.w;
        }
        g1_accum32(a4, 16, W0 + 64*128, cbase, h);
        if (valid) {
            float4* o4 = reinterpret_cast<float4*>(Pd + (size_t)n * 128 + cbase);
            #pragma unroll
            for (int i = 0; i < 8; i++)
                o4[i] = make_float4(h[4*i], h[4*i+1], h[4*i+2], h[4*i+3]);
        }
    }
}

// ------------- edge core (A'-factored, 2x64 chunks) -------------------------
// h = Pd[dst] + edgeT@W0[0:64] + nodeT[src]@W0[128:192]; edgeT += relu(h)@W1+b1
// srcI/dstI are position-order index arrays (CSR-permuted or original).

__global__ __launch_bounds__(256, 2) void k_edge_core2(
    float* __restrict__ edgeT, const float* __restrict__ Pd,
    const float* __restrict__ nodeT,
    const int* __restrict__ srcI, const int* __restrict__ dstI,
    const float* __restrict__ W0, const float* __restrict__ W1,
    const float* __restrict__ b1, int E) {
    __shared__ float sb[32 * 256];
    int e = blockIdx.x * 256 + threadIdx.x;
    bool valid = e < E;
    int ec = valid ? e : E - 1;
    int d = dstI[ec], s = srcI[ec];
    const float4* a4  = reinterpret_cast<const float4*>(edgeT + (size_t)ec * 64);
    const float4* s4  = reinterpret_cast<const float4*>(nodeT + (size_t)s * 64);
    const float4* pd4 = reinterpret_cast<const float4*>(Pd + (size_t)d * 128);

    float o[64];
    const float4* bv = reinterpret_cast<const float4*>(b1);
    #pragma unroll
    for (int i = 0; i < 16; i++) {
        float4 b = bv[i];
        o[4*i+0] = b.x; o[4*i+1] = b.y; o[4*i+2] = b.z; o[4*i+3] = b.w;
    }
    #pragma unroll
    for (int ch = 0; ch < 2; ch++) {
        int cbase = ch * 64;
        float h[64];
        #pragma unroll
        for (int i = 0; i < 16; i++) {
            float4 u = pd4[ch*16 + i];
            h[4*i+0] = u.x; h[4*i+1] = u.y; h[4*i+2] = u.z; h[4*i+3] = u.w;
        }
        g1_accum64(a4, 16, W0, cbase, h);            // edgeT rows 0..63
        g1_accum64(s4, 16, W0 + 128*128, cbase, h);  // src rows 128..191
        #pragma unroll
        for (int i = 0; i < 64; i++) h[i] = fmaxf(h[i], 0.0f);
        g2_accum64(sb, h,      W1, cbase,      64, o);
        g2_accum64(sb, h + 32, W1, cbase + 32, 64, o);
    }
    if (valid) {
        float4* eo4 = reinterpret_cast<float4*>(edgeT + (size_t)e * 64);
        #pragma unroll
        for (int i = 0; i < 16; i++) {
            float4 t = a4[i];
            t.x += o[4*i+0]; t.y += o[4*i+1];
            t.z += o[4*i+2]; t.w += o[4*i+3];
            eo4[i] = t;
        }
    }
}

// ------------- plan B edge core (all inline, original order) ----------------

__global__ __launch_bounds__(256, 2) void k_edge_core_B(
    float* __restrict__ edgeT, const float* __restrict__ nodeT,
    const int* __restrict__ src, const int* __restrict__ dst,
    const float* __restrict__ W0, const float* __restrict__ b0,
    const float* __restrict__ W1, const float* __restrict__ b1, int E) {
    __shared__ float sb[32 * 256];
    int e = blockIdx.x * 256 + threadIdx.x;
    bool valid = e < E;
    int ec = valid ? e : E - 1;
    int d = dst[ec], s = src[ec];
    const float4* a4 = reinterpret_cast<const float4*>(edgeT + (size_t)ec * 64);
    const float4* d4 = reinterpret_cast<const float4*>(nodeT + (size_t)d * 64);
    const float4* s4 = reinterpret_cast<const float4*>(nodeT + (size_t)s * 64);

    float o[64];
    const float4* bv = reinterpret_cast<const float4*>(b1);
    #pragma unroll
    for (int i = 0; i < 16; i++) {
        float4 b = bv[i];
        o[4*i+0] = b.x; o[4*i+1] = b.y; o[4*i+2] = b.z; o[4*i+3] = b.w;
    }
    #pragma unroll
    for (int ch = 0; ch < 4; ch++) {
        int cbase = ch * 32;
        float h[32];
        const float4* b0v = reinterpret_cast<const float4*>(b0 + cbase);
        #pragma unroll
        for (int i = 0; i < 8; i++) {
            float4 b = b0v[i];
            h[4*i+0] = b.x; h[4*i+1] = b.y; h[4*i+2] = b.z; h[4*i+3] = b.w;
        }
        g1_accum32(a4, 16, W0, cbase, h);
        g1_accum32(d4, 16, W0 + 64*128, cbase, h);
        g1_accum32(s4, 16, W0 + 128*128, cbase, h);
        #pragma unroll
        for (int i = 0; i < 32; i++) h[i] = fmaxf(h[i], 0.0f);
        g2_accum64(sb, h, W1, cbase, 64, o);
    }
    if (valid) {
        float4* eo4 = reinterpret_cast<float4*>(edgeT + (size_t)e * 64);
        #pragma unroll
        for (int i = 0; i < 16; i++) {
            float4 t = a4[i];
            t.x += o[4*i+0]; t.y += o[4*i+1];
            t.z += o[4*i+2]; t.w += o[4*i+3];
            eo4[i] = t;
        }
    }
}

// ------------- mean aggregation (fp64, order-invariant) ---------------------

// CSR-permuted edgeT: contiguous streaming over [beg,end)
__global__ __launch_bounds__(256) void k_agg_csr(
    const float* __restrict__ edgeT, const int* __restrict__ row_off,
    const float* __restrict__ inv_cnt, float* __restrict__ aggT, int N) {
    int n = blockIdx.x * 4 + (threadIdx.x >> 6);
    int lane = threadIdx.x & 63;
    if (n >= N) return;
    int beg = row_off[n], end = row_off[n + 1];
    double s = 0.0;
    for (int idx = beg; idx < end; idx++)
        s += (double)edgeT[(size_t)idx * 64 + lane];
    aggT[(size_t)n * 64 + lane] = (float)(s * (double)inv_cnt[n]);
}

// original-order edgeT: gather via elist
__global__ __launch_bounds__(256) void k_agg_gather(
    const float* __restrict__ edgeT, const int* __restrict__ row_off,
    const int* __restrict__ edge_list, const float* __restrict__ inv_cnt,
    float* __restrict__ aggT, int N) {
    int n = blockIdx.x * 4 + (threadIdx.x >> 6);
    int lane = threadIdx.x & 63;
    if (n >= N) return;
    int beg = row_off[n], end = row_off[n + 1];
    double s = 0.0;
    for (int idx = beg; idx < end; idx++) {
        int e = edge_list[idx];
        s += (double)edgeT[(size_t)e * 64 + lane];
    }
    aggT[(size_t)n * 64 + lane] = (float)(s * (double)inv_cnt[n]);
}

// ------------- node core ----------------------------------------------------

__global__ __launch_bounds__(256, 2) void k_node_core(
    const float* __restrict__ aggT, float* __restrict__ nodeT,
    const float* __restrict__ W0, const float* __restrict__ b0,
    const float* __restrict__ W1, const float* __restrict__ b1, int N) {
    __shared__ float sb[32 * 256];
    int n = blockIdx.x * 256 + threadIdx.x;
    bool valid = n < N;
    int nc = valid ? n : N - 1;
    const float4* g4 = reinterpret_cast<const float4*>(aggT + (size_t)nc * 64);
    const float4* t4 = reinterpret_cast<const float4*>(nodeT + (size_t)nc * 64);

    float o[64];
    const float4* bv = reinterpret_cast<const float4*>(b1);
    #pragma unroll
    for (int i = 0; i < 16; i++) {
        float4 b = bv[i];
        o[4*i+0] = b.x; o[4*i+1] = b.y; o[4*i+2] = b.z; o[4*i+3] = b.w;
    }
    #pragma unroll
    for (int ch = 0; ch < 4; ch++) {
        int cbase = ch * 32;
        float h[32];
        const float4* b0v = reinterpret_cast<const float4*>(b0 + cbase);
        #pragma unroll
        for (int i = 0; i < 8; i++) {
            float4 b = b0v[i];
            h[4*i+0] = b.x; h[4*i+1] = b.y; h[4*i+2] = b.z; h[4*i+3] = b.w;
        }
        g1_accum32(g4, 16, W0, cbase, h);
        g1_accum32(t4, 16, W0 + 64*128, cbase, h);
        #pragma unroll
        for (int i = 0; i < 32; i++) h[i] = fmaxf(h[i], 0.0f);
        g2_accum64(sb, h, W1, cbase, 64, o);
    }
    if (valid) {
        float4* nt4 = reinterpret_cast<float4*>(nodeT + (size_t)n * 64);
        #pragma unroll
        for (int i = 0; i < 16; i++) {
            float4 t = t4[i];
            t.x += o[4*i+0]; t.y += o[4*i+1];
            t.z += o[4*i+2]; t.w += o[4*i+3];
            nt4[i] = t;
        }
    }
}

// ------------- decoder (recomputes encoder head) ----------------------------

__global__ __launch_bounds__(256, 2) void k_decode(
    const float* __restrict__ nodeF, const float* __restrict__ embW,
    const float* __restrict__ encW0, const float* __restrict__ encW1,
    const float* __restrict__ encb1, const float* __restrict__ nodeT,
    const float* __restrict__ W0, const float* __restrict__ b0,
    const float* __restrict__ W1, const float* __restrict__ b1,
    float* __restrict__ out, int N) {
    __shared__ float sb[64 * 256];
    int t = threadIdx.x;
    int n = blockIdx.x * 256 + t;
    bool valid = n < N;
    int nc = valid ? n : N - 1;
    const float4* nf4 = reinterpret_cast<const float4*>(nodeF + (size_t)nc * 32);
    const float4* t4  = reinterpret_cast<const float4*>(nodeT + (size_t)nc * 64);
    float4 v7 = nf4[7];
    int p = (int)(v7.w + 0.5f);
    const float4* ew = reinterpret_cast<const float4*>(embW + p * 128);

    float head[64];
    const float4* ebv = reinterpret_cast<const float4*>(encb1);
    #pragma unroll
    for (int i = 0; i < 16; i++) {
        float4 b = ebv[i];
        head[4*i+0] = b.x; head[4*i+1] = b.y; head[4*i+2] = b.z; head[4*i+3] = b.w;
    }
    #pragma unroll
    for (int ch = 0; ch < 4; ch++) {
        int cbase = ch * 32;
        float h[32];
        #pragma unroll
        for (int i = 0; i < 8; i++) {
            float4 u = ew[ch*8 + i];
            h[4*i+0] = u.x; h[4*i+1] = u.y; h[4*i+2] = u.z; h[4*i+3] = u.w;
        }
        g1_accum32(nf4, 7, encW0, cbase, h);
        g1_tail3(v7.x, v7.y, v7.z, encW0 + 28*128, cbase, h);
        #pragma unroll
        for (int i = 0; i < 32; i++) h[i] = fmaxf(h[i], 0.0f);
        g2_accum64(sb, h, encW1, cbase, 128, head);
    }

    #pragma unroll
    for (int k = 0; k < 64; k++) sb[k * 256 + t] = head[k];
    __syncthreads();

    float h2[128];
    #pragma unroll
    for (int ch = 0; ch < 4; ch++) {
        int cbase = ch * 32;
        float* hc = &h2[ch * 32];
        const float4* b0v = reinterpret_cast<const float4*>(b0 + cbase);
        #pragma unroll
        for (int i = 0; i < 8; i++) {
            float4 b = b0v[i];
            hc[4*i+0] = b.x; hc[4*i+1] = b.y; hc[4*i+2] = b.z; hc[4*i+3] = b.w;
        }
        #pragma clang loop unroll(disable)
        for (int k = 0; k < 64; k++) {
            float hk = sb[k * 256 + t];
            const float4* w = reinterpret_cast<const float4*>(W0 + (size_t)k * 128 + cbase);
            #pragma unroll
            for (int cg = 0; cg < 8; cg++) {
                float4 wv = w[cg];
                hc[cg*4+0] = fmaf(hk, wv.x, hc[cg*4+0]);
                hc[cg*4+1] = fmaf(hk, wv.y, hc[cg*4+1]);
                hc[cg*4+2] = fmaf(hk, wv.z, hc[cg*4+2]);
                hc[cg*4+3] = fmaf(hk, wv.w, hc[cg*4+3]);
            }
        }
        g1_accum32(t4, 16, W0 + 64*128, cbase, hc);
    }
    __syncthreads();

    float o0 = b1[0], o1 = b1[1], o2 = b1[2];
    #pragma unroll
    for (int ch = 0; ch < 4; ch++) {
        int kb = ch * 32;
        #pragma unroll
        for (int k = 0; k < 32; k++) sb[k * 256 + t] = fmaxf(h2[kb + k], 0.0f);
        __syncthreads();
        #pragma clang loop unroll(disable)
        for (int k = 0; k < 32; k++) {
            float hk = sb[k * 256 + t];
            const float* w = W1 + (size_t)(kb + k) * 3;
            o0 = fmaf(hk, w[0], o0);
            o1 = fmaf(hk, w[1], o1);
            o2 = fmaf(hk, w[2], o2);
        }
        __syncthreads();
    }
    if (valid) {
        out[(size_t)n * 3 + 0] = o0;
        out[(size_t)n * 3 + 1] = o1;
        out[(size_t)n * 3 + 2] = o2;
    }
}

// ---------------------------------------------------------------------------

extern "C" void kernel_launch(void* const* d_in, const int* in_sizes, int n_in,
                              void* d_out, int out_size, void* d_ws, size_t ws_size,
                              hipStream_t stream) {
    const int*   edge_index = (const int*)  d_in[0];
    const float* nodeF      = (const float*)d_in[1];
    const float* edgeF      = (const float*)d_in[2];
    const float* emb        = (const float*)d_in[3];
    const float* enc_n_W0   = (const float*)d_in[4];
    const float* enc_n_b0   = (const float*)d_in[5];
    const float* enc_n_W1   = (const float*)d_in[6];
    const float* enc_n_b1   = (const float*)d_in[7];
    const float* enc_e_W0   = (const float*)d_in[8];
    const float* enc_e_b0   = (const float*)d_in[9];
    const float* enc_e_W1   = (const float*)d_in[10];
    const float* enc_e_b1   = (const float*)d_in[11];
    const float* core_e_W0  = (const float*)d_in[12];
    const float* core_e_b0  = (const float*)d_in[13];
    const float* core_e_W1  = (const float*)d_in[14];
    const float* core_e_b1  = (const float*)d_in[15];
    const float* core_n_W0  = (const float*)d_in[16];
    const float* core_n_b0  = (const float*)d_in[17];
    const float* core_n_W1  = (const float*)d_in[18];
    const float* core_n_b1  = (const float*)d_in[19];
    const float* dec_W0     = (const float*)d_in[20];
    const float* dec_b0     = (const float*)d_in[21];
    const float* dec_W1     = (const float*)d_in[22];
    const float* dec_b1     = (const float*)d_in[23];
    (void)n_in; (void)out_size;

    const int E = in_sizes[0] / 2;
    const int N = in_sizes[1] / 32;
    const int* src = edge_index;
    const int* dst = edge_index + E;

    auto al = [](size_t x) { return (x + 255) & ~(size_t)255; };
    const size_t szEdgeT = al((size_t)E * 64 * 4);
    const size_t szNodeT = al((size_t)N * 64 * 4);
    const size_t szP     = al((size_t)N * 128 * 4);
    const size_t szAgg   = al((size_t)N * 64 * 4);
    const size_t szElist = al((size_t)E * 4);
    const size_t szN4    = al((size_t)N * 4);
    const size_t szRow   = al((size_t)(N + 1) * 4);
    const size_t szEmbW  = al(2 * 128 * 4);
    const size_t base = szEdgeT + szNodeT + szElist + szRow + 3 * szN4 + szEmbW;
    const size_t needCSR = base + 2 * szElist + szP;  // src_p + dst_p + Pd (aggT alias)
    const size_t needAp  = base + szP;                // Pd (aggT alias)
    const int plan = (ws_size >= needCSR) ? 0 : (ws_size >= needAp) ? 1 : 2;

    char* ws = (char*)d_ws;
    size_t off = 0;
    auto carve = [&](size_t bytes) -> char* { char* p = ws + off; off += bytes; return p; };
    float* edgeT   = (float*)carve(szEdgeT);
    float* nodeT   = (float*)carve(szNodeT);
    int*   elist   = (int*)  carve(szElist);
    int*   row_off = (int*)  carve(szRow);
    int*   counts  = (int*)  carve(szN4);
    int*   cursor  = (int*)  carve(szN4);
    float* inv_cnt = (float*)carve(szN4);
    float* embW    = (float*)carve(szEmbW);
    int *src_p = nullptr, *dst_p = nullptr;
    float *Pd = nullptr, *aggT = nullptr;
    if (plan == 0) {
        src_p = (int*)carve(szElist);
        dst_p = (int*)carve(szElist);
        Pd = (float*)carve(szP); aggT = Pd;   // lifetime-disjoint alias
    } else if (plan == 1) {
        Pd = (float*)carve(szP); aggT = Pd;
    } else {
        aggT = (float*)carve(szAgg);
    }

    int blkE = (E + 255) / 256;
    int blkN = (N + 255) / 256;

    k_zero<<<(N + 255) / 256, 256, 0, stream>>>(counts, N);
    k_hist<<<blkE, 256, 0, stream>>>(dst, counts, E);
    k_scan<<<1, 1024, 0, stream>>>(counts, row_off, cursor, inv_cnt, N);
    k_fill<<<blkE, 256, 0, stream>>>(dst, cursor, elist, E);
    if (plan == 0)
        k_perm_idx<<<blkE, 256, 0, stream>>>(elist, src, dst, src_p, dst_p, E);

    k_embW<<<1, 128, 0, stream>>>(emb, enc_n_W0, enc_n_b0, embW);
    k_enc_node_tail<<<blkN, 256, 0, stream>>>(nodeF, embW, enc_n_W0, enc_n_W1,
                                              enc_n_b1, nodeT, N);
    k_enc_edge<<<blkE, 256, 0, stream>>>(edgeF, elist, (plan == 0) ? 1 : 0,
                                         enc_e_W0, enc_e_b0, enc_e_W1, enc_e_b1,
                                         edgeT, E);

    for (int step = 0; step < 3; step++) {
        if (plan == 0) {
            k_node_pre_d<<<blkN, 256, 0, stream>>>(nodeT, core_e_W0, core_e_b0, Pd, N);
            k_edge_core2<<<blkE, 256, 0, stream>>>(edgeT, Pd, nodeT, src_p, dst_p,
                                                   core_e_W0, core_e_W1, core_e_b1, E);
            k_agg_csr<<<(N + 3) / 4, 256, 0, stream>>>(edgeT, row_off, inv_cnt, aggT, N);
        } else if (plan == 1) {
            k_node_pre_d<<<blkN, 256, 0, stream>>>(nodeT, core_e_W0, core_e_b0, Pd, N);
            k_edge_core2<<<blkE, 256, 0, stream>>>(edgeT, Pd, nodeT, src, dst,
                                                   core_e_W0, core_e_W1, core_e_b1, E);
            k_agg_gather<<<(N + 3) / 4, 256, 0, stream>>>(edgeT, row_off, elist,
                                                          inv_cnt, aggT, N);
        } else {
            k_edge_core_B<<<blkE, 256, 0, stream>>>(edgeT, nodeT, src, dst,
                                                    core_e_W0, core_e_b0,
                                                    core_e_W1, core_e_b1, E);
            k_agg_gather<<<(N + 3) / 4, 256, 0, stream>>>(edgeT, row_off, elist,
                                                          inv_cnt, aggT, N);
        }
        k_node_core<<<blkN, 256, 0, stream>>>(aggT, nodeT, core_n_W0, core_n_b0,
                                              core_n_W1, core_n_b1, N);
    }
    k_decode<<<blkN, 256, 0, stream>>>(nodeF, embW, enc_n_W0, enc_n_W1, enc_n_b1,
                                       nodeT, dec_W0, dec_b0, dec_W1, dec_b1,
                                       (float*)d_out, N);
}